// Round 2
// baseline (2226.860 us; speedup 1.0000x reference)
//
#include <hip/hip_runtime.h>

typedef unsigned short u16;
typedef __attribute__((ext_vector_type(8))) __bf16 bf16x8;
typedef __attribute__((ext_vector_type(4))) float f32x4;

__device__ __forceinline__ float bf2f(u16 u) { return __uint_as_float(((unsigned)u) << 16); }
__device__ __forceinline__ u16 f2bf(float f) {
    unsigned x = __float_as_uint(f);
    x += 0x7fffu + ((x >> 16) & 1u);
    return (u16)(x >> 16);
}

// ---------------------------------------------------------------------------
// GEMM: C[M,N] = A[M,K] * B[N,K]^T  (bf16 in, fp32 acc), 128x128 tile, BK=32.
// grid: x = N/128, y = mTiles*S (split-K), z = batch.
// parts mode (outP): raw fp32 partials [z][ks][M][N].
// direct mode: bias/act/resid fused; outF fp32 [M][N] and/or outB bf16 [M][N].
// ---------------------------------------------------------------------------
__global__ __launch_bounds__(256) void d7_gemm(
    const u16* __restrict__ A, const u16* __restrict__ B,
    int N, int K, int kLen, int mTiles, int S,
    long aBS, long bBS,
    const float* __restrict__ bias, const float* __restrict__ alpha, int act,
    const float* __restrict__ resid, long residBS,
    float* __restrict__ outF, long oFBS,
    u16* __restrict__ outB, long oBBS,
    float* __restrict__ outP, long pMN)
{
    __shared__ u16 As[128 * 40];
    __shared__ u16 Bs[128 * 40];

    const int tid = threadIdx.x;
    const int wv = tid >> 6, lane = tid & 63;
    const int wm = wv >> 1, wn = wv & 1;
    const int bn = blockIdx.x;
    const int bm = blockIdx.y % mTiles;
    const int ks = blockIdx.y / mTiles;
    const int z  = blockIdx.z;
    const int kStart = ks * kLen;

    const int srow = tid >> 1;
    const int soff = (tid & 1) * 16;
    const u16* gA = A + z * aBS + (size_t)(bm * 128 + srow) * K + kStart + soff;
    const u16* gB = B + z * bBS + (size_t)(bn * 128 + srow) * K + kStart + soff;
    u16* lA = &As[srow * 40 + soff];
    u16* lB = &Bs[srow * 40 + soff];

    f32x4 acc[4][4] = {};

    for (int k0 = 0; k0 < kLen; k0 += 32) {
        __syncthreads();
        ((uint4*)lA)[0] = ((const uint4*)gA)[0];
        ((uint4*)lA)[1] = ((const uint4*)gA)[1];
        ((uint4*)lB)[0] = ((const uint4*)gB)[0];
        ((uint4*)lB)[1] = ((const uint4*)gB)[1];
        gA += 32; gB += 32;
        __syncthreads();

        bf16x8 a[4], b[4];
        #pragma unroll
        for (int mt = 0; mt < 4; ++mt)
            a[mt] = *reinterpret_cast<const bf16x8*>(&As[(wm * 64 + mt * 16 + (lane & 15)) * 40 + (lane >> 4) * 8]);
        #pragma unroll
        for (int nt = 0; nt < 4; ++nt)
            b[nt] = *reinterpret_cast<const bf16x8*>(&Bs[(wn * 64 + nt * 16 + (lane & 15)) * 40 + (lane >> 4) * 8]);
        #pragma unroll
        for (int mt = 0; mt < 4; ++mt)
            #pragma unroll
            for (int nt = 0; nt < 4; ++nt)
                acc[mt][nt] = __builtin_amdgcn_mfma_f32_16x16x32_bf16(a[mt], b[nt], acc[mt][nt], 0, 0, 0);
    }

    if (outP) {
        float* pp = outP + ((size_t)z * S + ks) * pMN;
        #pragma unroll
        for (int mt = 0; mt < 4; ++mt) {
            const int mg = bm * 128 + wm * 64 + mt * 16 + ((lane >> 4) << 2);
            #pragma unroll
            for (int nt = 0; nt < 4; ++nt) {
                const int ng = bn * 128 + wn * 64 + nt * 16 + (lane & 15);
                #pragma unroll
                for (int r = 0; r < 4; ++r)
                    pp[(size_t)(mg + r) * N + ng] = acc[mt][nt][r];
            }
        }
        return;
    }

    const float aval = (act == 1) ? alpha[0] : 0.0f;
    #pragma unroll
    for (int mt = 0; mt < 4; ++mt) {
        const int mg = bm * 128 + wm * 64 + mt * 16 + ((lane >> 4) << 2);
        float bv[4] = {0.f, 0.f, 0.f, 0.f};
        if (bias) {
            #pragma unroll
            for (int r = 0; r < 4; ++r) bv[r] = bias[mg + r];
        }
        #pragma unroll
        for (int nt = 0; nt < 4; ++nt) {
            const int ng = bn * 128 + wn * 64 + nt * 16 + (lane & 15);
            #pragma unroll
            for (int r = 0; r < 4; ++r) {
                float t = acc[mt][nt][r] + bv[r];
                if (act == 1) t = (t >= 0.f) ? t : aval * t;
                else if (act == 2) t = fmaxf(t, 0.f);
                if (resid) t += resid[z * residBS + (size_t)(mg + r) * N + ng];
                if (outF) outF[z * oFBS + (size_t)(mg + r) * N + ng] = t;
                if (outB) outB[z * oBBS + (size_t)(mg + r) * N + ng] = f2bf(t);
            }
        }
    }
}

// split-K reduce + bias/act/resid epilogue; N fixed at 4096 (m = i>>12)
__global__ __launch_bounds__(256) void d7_epi(
    const float* __restrict__ parts, int S, long sStride, long bStride,
    const float* __restrict__ bias, const float* __restrict__ alpha, int act,
    const float* __restrict__ resid, long residBS, float scale,
    float* __restrict__ out, long outBS, int total)
{
    int i = blockIdx.x * 256 + threadIdx.x;
    if (i >= total) return;
    int b = blockIdx.z;
    const float* p = parts + b * bStride + i;
    float s = 0.f;
    for (int t = 0; t < S; ++t) s += p[(size_t)t * sStride];
    s *= scale;
    if (bias) s += bias[i >> 12];
    if (act == 1) { float a = alpha[0]; s = (s >= 0.f) ? s : a * s; }
    else if (act == 2) s = fmaxf(s, 0.f);
    if (resid) s += resid[b * residBS + i];
    out[b * outBS + i] = s;
}

// ---------------------------------------------------------------------------
__global__ __launch_bounds__(256) void d7_cast(const float* __restrict__ src, u16* __restrict__ dst, int n) {
    int i = blockIdx.x * 256 + threadIdx.x;
    if (i < n) dst[i] = f2bf(src[i]);
}

__global__ __launch_bounds__(256) void d7_maxpool(const float* __restrict__ x, float* __restrict__ out) {
    int p = blockIdx.x * 256 + threadIdx.x;
    int c = blockIdx.y, b = blockIdx.z;
    int oh = p >> 6, ow = p & 63;
    const float* ip = x + ((size_t)b * 64 + c) * 16384;
    float v0 = ip[(2 * oh) * 128 + 2 * ow];
    float v1 = ip[(2 * oh) * 128 + 2 * ow + 1];
    float v2 = ip[(2 * oh + 1) * 128 + 2 * ow];
    float v3 = ip[(2 * oh + 1) * 128 + 2 * ow + 1];
    out[((size_t)b * 64 + c) * 4096 + p] = fmaxf(fmaxf(v0, v1), fmaxf(v2, v3));
}

// im2colT: img [b][Cin][64][64] fp32 -> patT [b][4096][Cin*9] bf16
__global__ __launch_bounds__(256) void d7_im2col(const float* __restrict__ img, u16* __restrict__ patT,
                                                 int Cin, long inBS, long outBS) {
    int K = Cin * 9;
    int k = blockIdx.x * 256 + threadIdx.x;
    if (k >= K) return;
    int p = blockIdx.y, b = blockIdx.z;
    int c = k / 9, k9 = k - c * 9;
    int h = p >> 6, w = p & 63;
    int y = h + k9 / 3 - 1, x = w + (k9 % 3) - 1;
    const float* ip = img + b * inBS;
    float v = (y >= 0 && y < 64 && x >= 0 && x < 64) ? ip[(size_t)c * 4096 + y * 64 + x] : 0.f;
    patT[b * outBS + (size_t)p * K + k] = f2bf(v);
}

// 1x1 conv + prelu -> bf16, transposed layout out[(off+p)*Co + co]
__global__ __launch_bounds__(256) void d7_c1T(
    const float* __restrict__ in, long inBS, const float* __restrict__ W,
    const float* __restrict__ bias, const float* __restrict__ alpha,
    int Ci, int Co, int P, u16* __restrict__ out, long outBS, int outOff)
{
    int p = blockIdx.x * 256 + threadIdx.x;
    if (p >= P) return;
    int co = blockIdx.y, b = blockIdx.z;
    const float* ip = in + b * inBS;
    float acc = bias[co];
    for (int ci = 0; ci < Ci; ++ci) acc += W[co * Ci + ci] * ip[(size_t)ci * P + p];
    float a = alpha[0];
    acc = (acc >= 0.f) ? acc : a * acc;
    out[b * outBS + (size_t)(outOff + p) * Co + co] = f2bf(acc);
}

// 1x1 conv + prelu -> bf16, row layout out[co*ld + off + p]
__global__ __launch_bounds__(256) void d7_c1N(
    const float* __restrict__ in, long inBS, const float* __restrict__ W,
    const float* __restrict__ bias, const float* __restrict__ alpha,
    int Ci, int P, u16* __restrict__ out, long outBS, int ld, int outOff)
{
    int p = blockIdx.x * 256 + threadIdx.x;
    if (p >= P) return;
    int co = blockIdx.y, b = blockIdx.z;
    const float* ip = in + b * inBS;
    float acc = bias[co];
    for (int ci = 0; ci < Ci; ++ci) acc += W[co * Ci + ci] * ip[(size_t)ci * P + p];
    float a = alpha[0];
    acc = (acc >= 0.f) ? acc : a * acc;
    out[b * outBS + (size_t)co * ld + outOff + p] = f2bf(acc);
}

// jax.image.resize bilinear antialias, 64 -> OS
template <int OS>
__device__ __forceinline__ void d7_taps(int o, int& i0, float w3[3]) {
    const float inv = 64.0f / OS;
    float s = (o + 0.5f) * inv - 0.5f;
    i0 = (int)ceilf(s - inv);
    float wsum = 0.f;
    #pragma unroll
    for (int t = 0; t < 3; ++t) {
        int y = i0 + t;
        float wt = 1.0f - fabsf((float)y - s) / inv;
        wt = (wt > 0.f && y >= 0 && y < 64) ? wt : 0.f;
        w3[t] = wt; wsum += wt;
    }
    float r = 1.0f / wsum;
    w3[0] *= r; w3[1] *= r; w3[2] *= r;
}

template <int OS>
__global__ __launch_bounds__(256) void d7_resize(const float* __restrict__ in, float* __restrict__ out, long out_bs) {
    int p = blockIdx.x * 256 + threadIdx.x;
    if (p >= OS * OS) return;
    int c = blockIdx.y, b = blockIdx.z;
    int oh = p / OS, ow = p - oh * OS;
    const float* img = in + ((size_t)b * 128 + c) * 4096;
    int y0, x0; float wy[3], wx[3];
    d7_taps<OS>(oh, y0, wy);
    d7_taps<OS>(ow, x0, wx);
    float sum = 0.f;
    #pragma unroll
    for (int iy = 0; iy < 3; ++iy) {
        if (wy[iy] <= 0.f) continue;
        float rs = 0.f;
        #pragma unroll
        for (int ix = 0; ix < 3; ++ix) {
            if (wx[ix] <= 0.f) continue;
            rs += wx[ix] * img[(y0 + iy) * 64 + (x0 + ix)];
        }
        sum += wy[iy] * rs;
    }
    out[(size_t)b * out_bs + (size_t)c * OS * OS + p] = sum;
}

__device__ __forceinline__ void d7_scale_lookup(int l, int& hs, int& ws_, int& HS, int& off) {
    if (l < 4096)      { int li = l;        HS = 64; hs = li >> 6; ws_ = li & 63;   off = 0; }
    else if (l < 7345) { int li = l - 4096; HS = 57; hs = li / 57; ws_ = li % 57;   off = 4096; }
    else if (l < 9946) { int li = l - 7345; HS = 51; hs = li / 51; ws_ = li % 51;   off = 7345; }
    else               { int li = l - 9946; HS = 44; hs = li / 44; ws_ = li % 44;   off = 9946; }
}

__global__ __launch_bounds__(256) void d7_ltab(int4* __restrict__ ltab) {
    int l = blockIdx.x * 256 + threadIdx.x;
    if (l >= 11904) return;
    int hs, ws_, HS, off;
    d7_scale_lookup(l, hs, ws_, HS, off);
    ltab[l] = make_int4(hs, ws_, HS, off);
}

// per-l channel sum of squares from refmT [l][64]
__global__ __launch_bounds__(256) void d7_s2(const u16* __restrict__ refmT, long BS,
                                             float* __restrict__ s2, long s2BS) {
    int l = blockIdx.x * 256 + threadIdx.x;
    if (l >= 11904) return;
    int b = blockIdx.z;
    const u16* r = refmT + b * BS + (size_t)l * 64;
    float s = 0.f;
    for (int c = 0; c < 64; ++c) { float v = bf2f(r[c]); s += v * v; }
    s2[b * s2BS + l] = s;
}

// rnorm[l] = 1 / max(sqrt(sum of 9-tap s2), 1e-4)
__global__ __launch_bounds__(256) void d7_norm9(const float* __restrict__ s2, long s2BS,
                                                const int4* __restrict__ ltab,
                                                float* __restrict__ rnorm, long rnBS) {
    int l = blockIdx.x * 256 + threadIdx.x;
    if (l >= 11904) return;
    int b = blockIdx.z;
    int4 t = ltab[l];
    const float* s = s2 + b * s2BS + t.w;
    float acc = 0.f;
    #pragma unroll
    for (int a = -1; a <= 1; ++a) {
        int y = t.x + a;
        if ((unsigned)y >= (unsigned)t.z) continue;
        #pragma unroll
        for (int bb = -1; bb <= 1; ++bb) {
            int x = t.y + bb;
            if ((unsigned)x >= (unsigned)t.z) continue;
            acc += s[y * t.z + x];
        }
    }
    rnorm[b * rnBS + l] = 1.0f / fmaxf(sqrtf(acc), 1e-4f);
}

// diagonal 9-tap stencil: out[p][l] = scale_l * sum_{a,b} in[(p+shift_ab)][(l+shift_ab)]
// shifts applied jointly in p-grid (64x64) and l's scale grid. in/out [4096][11904] bf16.
__global__ __launch_bounds__(256) void d7_stencil9(const u16* __restrict__ in, u16* __restrict__ out,
                                                   const float* __restrict__ rnorm,
                                                   const int4* __restrict__ ltab) {
    int l = blockIdx.x * 256 + threadIdx.x;
    if (l >= 11904) return;
    int p = blockIdx.y;
    int4 t = ltab[l];
    int h = p >> 6, w = p & 63;
    float s = 0.f;
    #pragma unroll
    for (int a = -1; a <= 1; ++a) {
        int y = t.x + a, ph = h + a;
        if ((unsigned)y >= (unsigned)t.z || (unsigned)ph >= 64u) continue;
        #pragma unroll
        for (int bb = -1; bb <= 1; ++bb) {
            int x = t.y + bb, pw = w + bb;
            if ((unsigned)x >= (unsigned)t.z || (unsigned)pw >= 64u) continue;
            s += bf2f(in[(size_t)(ph * 64 + pw) * 11904 + t.w + y * t.z + x]);
        }
    }
    if (rnorm) s *= rnorm[l];
    out[(size_t)p * 11904 + l] = f2bf(s);
}

// softmax over l in-place on bf16 [4096][11904]
__global__ __launch_bounds__(256) void d7_softmax(u16* __restrict__ sc) {
    const int LT = 11882, LTP = 11904, NI = 47;
    int p = blockIdx.x, tid = threadIdx.x, w = tid >> 6, lane = tid & 63;
    u16* row = sc + (size_t)p * LTP;
    float vals[NI];
    float m = -1e30f;
    #pragma unroll
    for (int j = 0; j < NI; ++j) {
        int l = tid + j * 256;
        float v = (l < LT) ? bf2f(row[l]) : -1e30f;
        vals[j] = v; m = fmaxf(m, v);
    }
    #pragma unroll
    for (int o = 1; o < 64; o <<= 1) m = fmaxf(m, __shfl_xor(m, o));
    __shared__ float red[4];
    if (lane == 0) red[w] = m;
    __syncthreads();
    m = fmaxf(fmaxf(red[0], red[1]), fmaxf(red[2], red[3]));
    __syncthreads();
    float s = 0.f;
    #pragma unroll
    for (int j = 0; j < NI; ++j) {
        float e = __expf((vals[j] - m) * 10.0f);
        vals[j] = e; s += e;
    }
    #pragma unroll
    for (int o = 1; o < 64; o <<= 1) s += __shfl_xor(s, o);
    if (lane == 0) red[w] = s;
    __syncthreads();
    float invZ = 1.0f / (red[0] + red[1] + red[2] + red[3]);
    #pragma unroll
    for (int j = 0; j < NI; ++j) {
        int l = tid + j * 256;
        if (l < LTP) row[l] = f2bf(vals[j] * invZ);
    }
}

// ---------------------------------------------------------------------------
extern "C" void kernel_launch(void* const* d_in, const int* in_sizes, int n_in,
                              void* d_out, int out_size, void* d_ws, size_t ws_size,
                              hipStream_t stream) {
    const float* x      = (const float*)d_in[0];
    const float* bb0_w  = (const float*)d_in[1];
    const float* bb0_b  = (const float*)d_in[2];
    const float* bb0_a  = (const float*)d_in[3];
    const float* rb1_w1 = (const float*)d_in[4];
    const float* rb1_b1 = (const float*)d_in[5];
    const float* rb1_w2 = (const float*)d_in[6];
    const float* rb1_b2 = (const float*)d_in[7];
    const float* pamb_w = (const float*)d_in[8];
    const float* pamb_b = (const float*)d_in[9];
    const float* pamb_a = (const float*)d_in[10];
    const float* pam_w  = (const float*)d_in[11];
    const float* pam_b  = (const float*)d_in[12];
    const float* pam_a  = (const float*)d_in[13];
    const float* paa_w  = (const float*)d_in[14];
    const float* paa_b  = (const float*)d_in[15];
    const float* paa_a  = (const float*)d_in[16];
    const float* rb2_w1 = (const float*)d_in[17];
    const float* rb2_b1 = (const float*)d_in[18];
    const float* rb2_w2 = (const float*)d_in[19];
    const float* rb2_b2 = (const float*)d_in[20];
    float* out = (float*)d_out;
    (void)in_sizes; (void)n_in; (void)out_size; (void)ws_size;

    char* wp = (char*)d_ws;
    auto alloc = [&](size_t nbytes) { void* p = wp; wp += (nbytes + 255) & ~(size_t)255; return p; };
    const size_t BIG = 4096ull * 11904 * 2;          // 97.5 MB
    void* big1   = alloc(BIG);                       // S0T / gT / patT
    void* big2   = alloc(BIG);                       // scT / split-K parts
    float* h0f   = (float*)alloc(2ull * 64 * 4096 * 4);
    float* h1f   = (float*)alloc(2ull * 128 * 4096 * 4);
    float* h2f   = (float*)alloc(2ull * 128 * 4096 * 4);
    float* paf   = (float*)alloc(2ull * 128 * 4096 * 4);
    float* tbuf  = (float*)alloc(2ull * 128 * 4096 * 4);
    float* refb  = (float*)alloc(2ull * 128 * 7786 * 4);
    u16* mbT     = (u16*)alloc(2ull * 4096 * 64 * 2);
    u16* refmT   = (u16*)alloc(2ull * 11904 * 64 * 2);
    u16* baseA   = (u16*)alloc(2ull * 128 * 11904 * 2);
    float* s2b   = (float*)alloc(2ull * 11904 * 4);
    float* rnorm = (float*)alloc(2ull * 11904 * 4);
    int4* ltab   = (int4*)alloc(11904ull * 16);
    u16* A0      = (u16*)alloc(73728ull * 2);
    u16* A1      = (u16*)alloc(147456ull * 2);
    u16* A2      = (u16*)alloc(147456ull * 2);
    u16* A3      = (u16*)alloc(147456ull * 2);
    u16* A4      = (u16*)alloc(147456ull * 2);

    u16* patT   = (u16*)big1;
    u16* S0T    = (u16*)big1;
    u16* gT     = (u16*)big1;
    u16* scT    = (u16*)big2;
    float* parts = (float*)big2;

    const long h2bs = 128L * 4096;
    const long pMN = 128L * 4096;
    const long refbs = 128L * 7786;
    const long mbTbs = 4096L * 64, rmTbs = 11904L * 64, baBS = 128L * 11904;

    // batch-fused conv3x3-as-GEMM with split-K=6 + epilogue
    auto conv = [&](const float* src, const u16* W, int Cin, const float* bias,
                    const float* alpha, int act, const float* resid, float* dst) {
        int K = Cin * 9;
        d7_im2col<<<dim3((K + 255) / 256, 4096, 2), 256, 0, stream>>>(src, patT, Cin, (long)Cin * 4096, 4096L * K);
        d7_gemm<<<dim3(32, 6, 2), 256, 0, stream>>>(W, patT, 4096, K, K / 6, 1, 6,
            0, 4096L * K, nullptr, nullptr, 0, nullptr, 0,
            nullptr, 0, nullptr, 0, parts, pMN);
        d7_epi<<<dim3(2048, 1, 2), 256, 0, stream>>>(parts, 6, pMN, 6 * pMN,
            bias, alpha, act, resid, h2bs, 1.0f, dst, h2bs, (int)pMN);
    };

    // weight casts
    d7_cast<<<dim3(288), 256, 0, stream>>>(bb0_w, A0, 73728);
    d7_cast<<<dim3(576), 256, 0, stream>>>(rb1_w1, A1, 147456);
    d7_cast<<<dim3(576), 256, 0, stream>>>(rb1_w2, A2, 147456);
    d7_cast<<<dim3(576), 256, 0, stream>>>(rb2_w1, A3, 147456);
    d7_cast<<<dim3(576), 256, 0, stream>>>(rb2_w2, A4, 147456);
    d7_ltab<<<dim3(47), 256, 0, stream>>>(ltab);

    d7_maxpool<<<dim3(16, 64, 2), 256, 0, stream>>>(x, h0f);

    // BasicBlock + ResBlock1
    conv(h0f, A0, 64, bb0_b, bb0_a, 1, nullptr, h1f);
    conv(h1f, A1, 128, rb1_b1, nullptr, 2, nullptr, tbuf);
    conv(tbuf, A2, 128, rb1_b2, nullptr, 0, h1f, h2f);

    // pyramid resizes
    d7_resize<57><<<dim3(13, 128, 2), 256, 0, stream>>>(h2f, refb, refbs);
    d7_resize<51><<<dim3(11, 128, 2), 256, 0, stream>>>(h2f, refb + 3249L * 128, refbs);
    d7_resize<44><<<dim3(8, 128, 2), 256, 0, stream>>>(h2f, refb + 5850L * 128, refbs);

    // 1x1 convs -> bf16 operand layouts
    d7_c1T<<<dim3(16, 64, 2), 256, 0, stream>>>(h2f, h2bs, pamb_w, pamb_b, pamb_a, 128, 64, 4096, mbT, mbTbs, 0);
    d7_c1T<<<dim3(16, 64, 2), 256, 0, stream>>>(h2f, h2bs, pam_w, pam_b, pam_a, 128, 64, 4096, refmT, rmTbs, 0);
    d7_c1T<<<dim3(13, 64, 2), 256, 0, stream>>>(refb, refbs, pam_w, pam_b, pam_a, 128, 64, 3249, refmT, rmTbs, 4096);
    d7_c1T<<<dim3(11, 64, 2), 256, 0, stream>>>(refb + 3249L * 128, refbs, pam_w, pam_b, pam_a, 128, 64, 2601, refmT, rmTbs, 7345);
    d7_c1T<<<dim3(8, 64, 2), 256, 0, stream>>>(refb + 5850L * 128, refbs, pam_w, pam_b, pam_a, 128, 64, 1936, refmT, rmTbs, 9946);
    hipMemsetAsync(baseA, 0, 2ull * 128 * 11904 * 2, stream);   // zero pad columns l in [11882,11904)
    d7_c1N<<<dim3(16, 128, 2), 256, 0, stream>>>(h2f, h2bs, paa_w, paa_b, paa_a, 128, 4096, baseA, baBS, 11904, 0);
    d7_c1N<<<dim3(13, 128, 2), 256, 0, stream>>>(refb, refbs, paa_w, paa_b, paa_a, 128, 3249, baseA, baBS, 11904, 4096);
    d7_c1N<<<dim3(11, 128, 2), 256, 0, stream>>>(refb + 3249L * 128, refbs, paa_w, paa_b, paa_a, 128, 2601, baseA, baBS, 11904, 7345);
    d7_c1N<<<dim3(8, 128, 2), 256, 0, stream>>>(refb + 5850L * 128, refbs, paa_w, paa_b, paa_a, 128, 1936, baseA, baBS, 11904, 9946);

    // patch norms
    d7_s2<<<dim3(47, 1, 2), 256, 0, stream>>>(refmT, rmTbs, s2b, 11904);
    d7_norm9<<<dim3(47, 1, 2), 256, 0, stream>>>(s2b, 11904, ltab, rnorm, 11904);

    // attention core, per batch
    for (int b = 0; b < 2; ++b) {
        // S0T[p][l] = sum_c mb[c,p]*refm[c,l]
        d7_gemm<<<dim3(93, 32, 1), 256, 0, stream>>>(mbT + b * mbTbs, refmT + b * rmTbs,
            11904, 64, 64, 32, 1, 0, 0, nullptr, nullptr, 0, nullptr, 0,
            nullptr, 0, S0T, 0, nullptr, 0);
        d7_stencil9<<<dim3(47, 4096), 256, 0, stream>>>(S0T, scT, rnorm + b * 11904, ltab);
        d7_softmax<<<dim3(4096), 256, 0, stream>>>(scT);
        d7_stencil9<<<dim3(47, 4096), 256, 0, stream>>>(scT, gT, nullptr, ltab);
        // out_pa = h2f + 0.25 * baseA · gT^T   (split-K = 12)
        d7_gemm<<<dim3(32, 12, 1), 256, 0, stream>>>(baseA + b * baBS, gT,
            4096, 11904, 992, 1, 12, 0, 0, nullptr, nullptr, 0, nullptr, 0,
            nullptr, 0, nullptr, 0, parts, pMN);
        d7_epi<<<dim3(2048, 1, 1), 256, 0, stream>>>(parts, 12, pMN, 0,
            nullptr, nullptr, 0, h2f + b * h2bs, 0, 0.25f, paf + b * h2bs, 0, (int)pMN);
    }

    // ResBlock2 -> d_out
    conv(paf, A3, 128, rb2_b1, nullptr, 2, nullptr, tbuf);
    conv(tbuf, A4, 128, rb2_b2, nullptr, 0, paf, out);
}

// Round 3
// 1086.724 us; speedup vs baseline: 2.0492x; 2.0492x over previous
//
#include <hip/hip_runtime.h>

typedef unsigned short u16;
typedef __attribute__((ext_vector_type(8))) __bf16 bf16x8;
typedef __attribute__((ext_vector_type(8))) unsigned short ushort8;
typedef __attribute__((ext_vector_type(4))) float f32x4;

__device__ __forceinline__ float bf2f(u16 u) { return __uint_as_float(((unsigned)u) << 16); }
__device__ __forceinline__ u16 f2bf(float f) {
    unsigned x = __float_as_uint(f);
    x += 0x7fffu + ((x >> 16) & 1u);
    return (u16)(x >> 16);
}

// Padded l-space: per-scale (HS+2) rows x W' cols with zero border, W' mult of 8.
// scale0: HS=64 W=72 off=0      (66*72=4752)
// scale1: HS=57 W=64 off=4752   (59*64=3776)
// scale2: HS=51 W=56 off=8528   (53*56=2968)
// scale3: HS=44 W=48 off=11496  (46*48=2208) -> 13704, dead zone to L=13824 (108*128)
#define LP 13824

// ---------------------------------------------------------------------------
// GEMM: C[M,N] = A[M,K] * B[N,K]^T  (bf16 in, fp32 acc), 128x128 tile, BK=32.
// ---------------------------------------------------------------------------
__global__ __launch_bounds__(256) void d7_gemm(
    const u16* __restrict__ A, const u16* __restrict__ B,
    int N, int K, int kLen, int mTiles, int S,
    long aBS, long bBS,
    const float* __restrict__ bias, const float* __restrict__ alpha, int act,
    const float* __restrict__ resid, long residBS,
    float* __restrict__ outF, long oFBS,
    u16* __restrict__ outB, long oBBS,
    float* __restrict__ outP, long pMN)
{
    __shared__ u16 As[128 * 40];
    __shared__ u16 Bs[128 * 40];

    const int tid = threadIdx.x;
    const int wv = tid >> 6, lane = tid & 63;
    const int wm = wv >> 1, wn = wv & 1;
    const int bn = blockIdx.x;
    const int bm = blockIdx.y % mTiles;
    const int ks = blockIdx.y / mTiles;
    const int z  = blockIdx.z;
    const int kStart = ks * kLen;

    const int srow = tid >> 1;
    const int soff = (tid & 1) * 16;
    const u16* gA = A + z * aBS + (size_t)(bm * 128 + srow) * K + kStart + soff;
    const u16* gB = B + z * bBS + (size_t)(bn * 128 + srow) * K + kStart + soff;
    u16* lA = &As[srow * 40 + soff];
    u16* lB = &Bs[srow * 40 + soff];

    f32x4 acc[4][4] = {};

    for (int k0 = 0; k0 < kLen; k0 += 32) {
        __syncthreads();
        ((uint4*)lA)[0] = ((const uint4*)gA)[0];
        ((uint4*)lA)[1] = ((const uint4*)gA)[1];
        ((uint4*)lB)[0] = ((const uint4*)gB)[0];
        ((uint4*)lB)[1] = ((const uint4*)gB)[1];
        gA += 32; gB += 32;
        __syncthreads();

        bf16x8 a[4], b[4];
        #pragma unroll
        for (int mt = 0; mt < 4; ++mt)
            a[mt] = *reinterpret_cast<const bf16x8*>(&As[(wm * 64 + mt * 16 + (lane & 15)) * 40 + (lane >> 4) * 8]);
        #pragma unroll
        for (int nt = 0; nt < 4; ++nt)
            b[nt] = *reinterpret_cast<const bf16x8*>(&Bs[(wn * 64 + nt * 16 + (lane & 15)) * 40 + (lane >> 4) * 8]);
        #pragma unroll
        for (int mt = 0; mt < 4; ++mt)
            #pragma unroll
            for (int nt = 0; nt < 4; ++nt)
                acc[mt][nt] = __builtin_amdgcn_mfma_f32_16x16x32_bf16(a[mt], b[nt], acc[mt][nt], 0, 0, 0);
    }

    if (outP) {
        float* pp = outP + ((size_t)z * S + ks) * pMN;
        #pragma unroll
        for (int mt = 0; mt < 4; ++mt) {
            const int mg = bm * 128 + wm * 64 + mt * 16 + ((lane >> 4) << 2);
            #pragma unroll
            for (int nt = 0; nt < 4; ++nt) {
                const int ng = bn * 128 + wn * 64 + nt * 16 + (lane & 15);
                #pragma unroll
                for (int r = 0; r < 4; ++r)
                    pp[(size_t)(mg + r) * N + ng] = acc[mt][nt][r];
            }
        }
        return;
    }

    const float aval = (act == 1) ? alpha[0] : 0.0f;
    #pragma unroll
    for (int mt = 0; mt < 4; ++mt) {
        const int mg = bm * 128 + wm * 64 + mt * 16 + ((lane >> 4) << 2);
        float bv[4] = {0.f, 0.f, 0.f, 0.f};
        if (bias) {
            #pragma unroll
            for (int r = 0; r < 4; ++r) bv[r] = bias[mg + r];
        }
        #pragma unroll
        for (int nt = 0; nt < 4; ++nt) {
            const int ng = bn * 128 + wn * 64 + nt * 16 + (lane & 15);
            #pragma unroll
            for (int r = 0; r < 4; ++r) {
                float t = acc[mt][nt][r] + bv[r];
                if (act == 1) t = (t >= 0.f) ? t : aval * t;
                else if (act == 2) t = fmaxf(t, 0.f);
                if (resid) t += resid[z * residBS + (size_t)(mg + r) * N + ng];
                if (outF) outF[z * oFBS + (size_t)(mg + r) * N + ng] = t;
                if (outB) outB[z * oBBS + (size_t)(mg + r) * N + ng] = f2bf(t);
            }
        }
    }
}

// split-K reduce + bias/act/resid epilogue; N fixed 4096 (m = i>>12)
__global__ __launch_bounds__(256) void d7_epi(
    const float* __restrict__ parts, int S, long sStride, long bStride,
    const float* __restrict__ bias, const float* __restrict__ alpha, int act,
    const float* __restrict__ resid, long residBS, float scale,
    float* __restrict__ out, long outBS, int total)
{
    int i = blockIdx.x * 256 + threadIdx.x;
    if (i >= total) return;
    int b = blockIdx.z;
    const float* p = parts + b * bStride + i;
    float s = 0.f;
    for (int t = 0; t < S; ++t) s += p[(size_t)t * sStride];
    s *= scale;
    if (bias) s += bias[i >> 12];
    if (act == 1) { float a = alpha[0]; s = (s >= 0.f) ? s : a * s; }
    else if (act == 2) s = fmaxf(s, 0.f);
    if (resid) s += resid[b * residBS + i];
    out[b * outBS + i] = s;
}

// ---------------------------------------------------------------------------
__global__ __launch_bounds__(256) void d7_cast(const float* __restrict__ src, u16* __restrict__ dst, int n) {
    int i = blockIdx.x * 256 + threadIdx.x;
    if (i < n) dst[i] = f2bf(src[i]);
}

__global__ __launch_bounds__(256) void d7_maxpool(const float* __restrict__ x, float* __restrict__ out) {
    int p = blockIdx.x * 256 + threadIdx.x;
    int c = blockIdx.y, b = blockIdx.z;
    int oh = p >> 6, ow = p & 63;
    const float* ip = x + ((size_t)b * 64 + c) * 16384;
    float v0 = ip[(2 * oh) * 128 + 2 * ow];
    float v1 = ip[(2 * oh) * 128 + 2 * ow + 1];
    float v2 = ip[(2 * oh + 1) * 128 + 2 * ow];
    float v3 = ip[(2 * oh + 1) * 128 + 2 * ow + 1];
    out[((size_t)b * 64 + c) * 4096 + p] = fmaxf(fmaxf(v0, v1), fmaxf(v2, v3));
}

__global__ __launch_bounds__(256) void d7_im2col(const float* __restrict__ img, u16* __restrict__ patT,
                                                 int Cin, long inBS, long outBS) {
    int K = Cin * 9;
    int k = blockIdx.x * 256 + threadIdx.x;
    if (k >= K) return;
    int p = blockIdx.y, b = blockIdx.z;
    int c = k / 9, k9 = k - c * 9;
    int h = p >> 6, w = p & 63;
    int y = h + k9 / 3 - 1, x = w + (k9 % 3) - 1;
    const float* ip = img + b * inBS;
    float v = (y >= 0 && y < 64 && x >= 0 && x < 64) ? ip[(size_t)c * 4096 + y * 64 + x] : 0.f;
    patT[b * outBS + (size_t)p * K + k] = f2bf(v);
}

// 1x1 conv (Ci=128) + prelu -> bf16 at padded index, K-major: out[lp*64+co]
__global__ __launch_bounds__(256) void d7_c1T(
    const float* __restrict__ in, long inBS, const float* __restrict__ Wm,
    const float* __restrict__ bias, const float* __restrict__ alpha,
    int P, u16* __restrict__ out, long outBS, int HS, int Wp, int off)
{
    int p = blockIdx.x * 256 + threadIdx.x;
    if (p >= P) return;
    int co = blockIdx.y, b = blockIdx.z;
    const float* ip = in + b * inBS;
    float acc = bias[co];
    for (int ci = 0; ci < 128; ++ci) acc += Wm[co * 128 + ci] * ip[(size_t)ci * P + p];
    float a = alpha[0];
    acc = (acc >= 0.f) ? acc : a * acc;
    int hs = p / HS, ws = p - hs * HS;
    int lp = off + (hs + 1) * Wp + ws + 1;
    out[b * outBS + (size_t)lp * 64 + co] = f2bf(acc);
}

// 1x1 conv (Ci=128) + prelu -> bf16 row layout: out[co*LP + lp]
__global__ __launch_bounds__(256) void d7_c1N(
    const float* __restrict__ in, long inBS, const float* __restrict__ Wm,
    const float* __restrict__ bias, const float* __restrict__ alpha,
    int P, u16* __restrict__ out, long outBS, int HS, int Wp, int off)
{
    int p = blockIdx.x * 256 + threadIdx.x;
    if (p >= P) return;
    int co = blockIdx.y, b = blockIdx.z;
    const float* ip = in + b * inBS;
    float acc = bias[co];
    for (int ci = 0; ci < 128; ++ci) acc += Wm[co * 128 + ci] * ip[(size_t)ci * P + p];
    float a = alpha[0];
    acc = (acc >= 0.f) ? acc : a * acc;
    int hs = p / HS, ws = p - hs * HS;
    int lp = off + (hs + 1) * Wp + ws + 1;
    out[b * outBS + (size_t)co * LP + lp] = f2bf(acc);
}

// jax.image.resize bilinear antialias, 64 -> OS
template <int OS>
__device__ __forceinline__ void d7_taps(int o, int& i0, float w3[3]) {
    const float inv = 64.0f / OS;
    float s = (o + 0.5f) * inv - 0.5f;
    i0 = (int)ceilf(s - inv);
    float wsum = 0.f;
    #pragma unroll
    for (int t = 0; t < 3; ++t) {
        int y = i0 + t;
        float wt = 1.0f - fabsf((float)y - s) / inv;
        wt = (wt > 0.f && y >= 0 && y < 64) ? wt : 0.f;
        w3[t] = wt; wsum += wt;
    }
    float r = 1.0f / wsum;
    w3[0] *= r; w3[1] *= r; w3[2] *= r;
}

template <int OS>
__global__ __launch_bounds__(256) void d7_resize(const float* __restrict__ in, float* __restrict__ out, long out_bs) {
    int p = blockIdx.x * 256 + threadIdx.x;
    if (p >= OS * OS) return;
    int c = blockIdx.y, b = blockIdx.z;
    int oh = p / OS, ow = p - oh * OS;
    const float* img = in + ((size_t)b * 128 + c) * 4096;
    int y0, x0; float wy[3], wx[3];
    d7_taps<OS>(oh, y0, wy);
    d7_taps<OS>(ow, x0, wx);
    float sum = 0.f;
    #pragma unroll
    for (int iy = 0; iy < 3; ++iy) {
        if (wy[iy] <= 0.f) continue;
        float rs = 0.f;
        #pragma unroll
        for (int ix = 0; ix < 3; ++ix) {
            if (wx[ix] <= 0.f) continue;
            rs += wx[ix] * img[(y0 + iy) * 64 + (x0 + ix)];
        }
        sum += wy[iy] * rs;
    }
    out[(size_t)b * out_bs + (size_t)c * OS * OS + p] = sum;
}

__device__ __forceinline__ int d7_scaleW(int l) {
    return (l < 4752) ? 72 : (l < 8528) ? 64 : (l < 11496) ? 56 : 48;
}

// s2[l'] = sum_c refmT_pad[l'][c]^2
__global__ __launch_bounds__(256) void d7_s2(const u16* __restrict__ refmT, float* __restrict__ s2) {
    int l = blockIdx.x * 256 + threadIdx.x;
    if (l >= LP) return;
    int zb = blockIdx.z;
    const u16* r = refmT + (size_t)zb * LP * 64 + (size_t)l * 64;
    float s = 0.f;
    #pragma unroll
    for (int c8 = 0; c8 < 8; ++c8) {
        ushort8 v = *reinterpret_cast<const ushort8*>(r + c8 * 8);
        #pragma unroll
        for (int i = 0; i < 8; ++i) { float f = bf2f(v[i]); s += f * f; }
    }
    s2[zb * LP + l] = s;
}

// rnorm[l'] = interior ? 1/max(sqrt(9-tap sum of s2),1e-4) : 0
__global__ __launch_bounds__(256) void d7_rnormk(const float* __restrict__ s2, float* __restrict__ rnorm) {
    int l = blockIdx.x * 256 + threadIdx.x;
    if (l >= LP) return;
    int zb = blockIdx.z;
    int off, W, HS;
    if (l < 4752)       { off = 0;     W = 72; HS = 64; }
    else if (l < 8528)  { off = 4752;  W = 64; HS = 57; }
    else if (l < 11496) { off = 8528;  W = 56; HS = 51; }
    else                { off = 11496; W = 48; HS = 44; }
    int li = l - off, y = li / W, x = li - y * W;
    float v = 0.f;
    if (y >= 1 && y <= HS && x >= 1 && x <= HS) {
        const float* s = s2 + zb * LP;
        float a = 0.f;
        #pragma unroll
        for (int dy = -1; dy <= 1; ++dy)
            #pragma unroll
            for (int dx = -1; dx <= 1; ++dx)
                a += s[l + dy * W + dx];
        v = 1.f / fmaxf(sqrtf(a), 1e-4f);
    }
    rnorm[zb * LP + l] = v;
}

// stencil1: scT[p][l'] = interior ? rnorm * sum_{a,b} S0T[p+64a+b][l'+aW+b] : -1e4
// in/out front-padded allocs. Masks (ph,pw) are block-uniform (p = blockIdx.y).
__global__ __launch_bounds__(256) void d7_st1(const u16* __restrict__ in, u16* __restrict__ out,
                                              const float* __restrict__ rnorm) {
    int vg = blockIdx.x * 256 + threadIdx.x;
    if (vg >= LP / 8) return;
    int l8 = vg << 3;
    int p = blockIdx.y;
    int h = p >> 6, w = p & 63;
    int W = d7_scaleW(l8);
    float acc[8] = {0.f, 0.f, 0.f, 0.f, 0.f, 0.f, 0.f, 0.f};
    #pragma unroll
    for (int a = -1; a <= 1; ++a) {
        int ph = h + a;
        if ((unsigned)ph >= 64u) continue;
        #pragma unroll
        for (int b = -1; b <= 1; ++b) {
            int pw = w + b;
            if ((unsigned)pw >= 64u) continue;
            const u16* rp = in + (size_t)(p + a * 64 + b) * LP + l8 + a * W;
            ushort8 v = *reinterpret_cast<const ushort8*>(rp);
            if (b == 0) {
                #pragma unroll
                for (int i = 0; i < 8; ++i) acc[i] += bf2f(v[i]);
            } else if (b == -1) {
                acc[0] += bf2f(rp[-1]);
                #pragma unroll
                for (int i = 1; i < 8; ++i) acc[i] += bf2f(v[i - 1]);
            } else {
                acc[7] += bf2f(rp[8]);
                #pragma unroll
                for (int i = 0; i < 7; ++i) acc[i] += bf2f(v[i + 1]);
            }
        }
    }
    const float4 rn0 = *reinterpret_cast<const float4*>(rnorm + l8);
    const float4 rn1 = *reinterpret_cast<const float4*>(rnorm + l8 + 4);
    float rn[8] = {rn0.x, rn0.y, rn0.z, rn0.w, rn1.x, rn1.y, rn1.z, rn1.w};
    ushort8 res;
    #pragma unroll
    for (int i = 0; i < 8; ++i)
        res[i] = f2bf((rn[i] != 0.f) ? acc[i] * rn[i] : -1e4f);
    *reinterpret_cast<ushort8*>(out + (size_t)p * LP + l8) = res;
}

// per-row softmax stats: stat[p] = (max, 1/Z). Pads (-1e4) vanish under exp.
__global__ __launch_bounds__(256) void d7_stats(const u16* __restrict__ sc, float2* __restrict__ stat) {
    int p = blockIdx.x, tid = threadIdx.x, wv = tid >> 6, lane = tid & 63;
    const u16* row = sc + (size_t)p * LP;
    float m = -3e38f;
    #pragma unroll
    for (int it = 0; it < 7; ++it) {
        int vg = tid + it * 256;
        if (vg < LP / 8) {
            ushort8 v = *reinterpret_cast<const ushort8*>(row + vg * 8);
            #pragma unroll
            for (int i = 0; i < 8; ++i) m = fmaxf(m, bf2f(v[i]));
        }
    }
    #pragma unroll
    for (int o = 1; o < 64; o <<= 1) m = fmaxf(m, __shfl_xor(m, o));
    __shared__ float red[4];
    if (lane == 0) red[wv] = m;
    __syncthreads();
    m = fmaxf(fmaxf(red[0], red[1]), fmaxf(red[2], red[3]));
    __syncthreads();
    float s = 0.f;
    #pragma unroll
    for (int it = 0; it < 7; ++it) {
        int vg = tid + it * 256;
        if (vg < LP / 8) {
            ushort8 v = *reinterpret_cast<const ushort8*>(row + vg * 8);
            #pragma unroll
            for (int i = 0; i < 8; ++i) s += __expf((bf2f(v[i]) - m) * 10.f);
        }
    }
    #pragma unroll
    for (int o = 1; o < 64; o <<= 1) s += __shfl_xor(s, o);
    if (lane == 0) red[wv] = s;
    __syncthreads();
    if (tid == 0) {
        float Z = red[0] + red[1] + red[2] + red[3];
        stat[p] = make_float2(m, 1.0f / Z);
    }
}

// stencil2: gT[p][l'] = interior ? sum_{a,b} exp(10*(scT[r][c]-m_r))*invZ_r : 0
__global__ __launch_bounds__(256) void d7_st2(const u16* __restrict__ in,
                                              const float2* __restrict__ stat,
                                              const float* __restrict__ rnorm,
                                              u16* __restrict__ out) {
    int vg = blockIdx.x * 256 + threadIdx.x;
    if (vg >= LP / 8) return;
    int l8 = vg << 3;
    int p = blockIdx.y;
    int h = p >> 6, w = p & 63;
    int W = d7_scaleW(l8);
    float acc[8] = {0.f, 0.f, 0.f, 0.f, 0.f, 0.f, 0.f, 0.f};
    #pragma unroll
    for (int a = -1; a <= 1; ++a) {
        int ph = h + a;
        if ((unsigned)ph >= 64u) continue;
        #pragma unroll
        for (int b = -1; b <= 1; ++b) {
            int pw = w + b;
            if ((unsigned)pw >= 64u) continue;
            int r = p + a * 64 + b;
            float2 st = stat[r];
            const u16* rp = in + (size_t)r * LP + l8 + a * W;
            ushort8 v = *reinterpret_cast<const ushort8*>(rp);
            if (b == 0) {
                #pragma unroll
                for (int i = 0; i < 8; ++i) acc[i] += __expf((bf2f(v[i]) - st.x) * 10.f) * st.y;
            } else if (b == -1) {
                acc[0] += __expf((bf2f(rp[-1]) - st.x) * 10.f) * st.y;
                #pragma unroll
                for (int i = 1; i < 8; ++i) acc[i] += __expf((bf2f(v[i - 1]) - st.x) * 10.f) * st.y;
            } else {
                acc[7] += __expf((bf2f(rp[8]) - st.x) * 10.f) * st.y;
                #pragma unroll
                for (int i = 0; i < 7; ++i) acc[i] += __expf((bf2f(v[i + 1]) - st.x) * 10.f) * st.y;
            }
        }
    }
    const float4 rn0 = *reinterpret_cast<const float4*>(rnorm + l8);
    const float4 rn1 = *reinterpret_cast<const float4*>(rnorm + l8 + 4);
    float rn[8] = {rn0.x, rn0.y, rn0.z, rn0.w, rn1.x, rn1.y, rn1.z, rn1.w};
    ushort8 res;
    #pragma unroll
    for (int i = 0; i < 8; ++i)
        res[i] = f2bf((rn[i] != 0.f) ? acc[i] : 0.f);
    *reinterpret_cast<ushort8*>(out + (size_t)p * LP + l8) = res;
}

// ---------------------------------------------------------------------------
extern "C" void kernel_launch(void* const* d_in, const int* in_sizes, int n_in,
                              void* d_out, int out_size, void* d_ws, size_t ws_size,
                              hipStream_t stream) {
    const float* x      = (const float*)d_in[0];
    const float* bb0_w  = (const float*)d_in[1];
    const float* bb0_b  = (const float*)d_in[2];
    const float* bb0_a  = (const float*)d_in[3];
    const float* rb1_w1 = (const float*)d_in[4];
    const float* rb1_b1 = (const float*)d_in[5];
    const float* rb1_w2 = (const float*)d_in[6];
    const float* rb1_b2 = (const float*)d_in[7];
    const float* pamb_w = (const float*)d_in[8];
    const float* pamb_b = (const float*)d_in[9];
    const float* pamb_a = (const float*)d_in[10];
    const float* pam_w  = (const float*)d_in[11];
    const float* pam_b  = (const float*)d_in[12];
    const float* pam_a  = (const float*)d_in[13];
    const float* paa_w  = (const float*)d_in[14];
    const float* paa_b  = (const float*)d_in[15];
    const float* paa_a  = (const float*)d_in[16];
    const float* rb2_w1 = (const float*)d_in[17];
    const float* rb2_b1 = (const float*)d_in[18];
    const float* rb2_w2 = (const float*)d_in[19];
    const float* rb2_b2 = (const float*)d_in[20];
    float* out = (float*)d_out;
    (void)in_sizes; (void)n_in; (void)out_size; (void)ws_size;

    char* wp = (char*)d_ws;
    auto alloc = [&](size_t nbytes) { void* p = wp; wp += (nbytes + 255) & ~(size_t)255; return p; };
    const size_t BIG = 4096ull * LP * 2;             // 113 MB
    char* big1r  = (char*)alloc(BIG + 1024);
    char* big2r  = (char*)alloc(BIG + 1024);
    float* h0f   = (float*)alloc(2ull * 64 * 4096 * 4);
    float* h1f   = (float*)alloc(2ull * 128 * 4096 * 4);
    float* h2f   = (float*)alloc(2ull * 128 * 4096 * 4);
    float* paf   = (float*)alloc(2ull * 128 * 4096 * 4);
    float* tbuf  = (float*)alloc(2ull * 128 * 4096 * 4);
    float* refb  = (float*)alloc(2ull * 128 * 7786 * 4);
    u16* mbT     = (u16*)alloc(2ull * 4096 * 64 * 2);
    u16* refmT   = (u16*)alloc(2ull * LP * 64 * 2);
    u16* baseA   = (u16*)alloc(2ull * 128 * LP * 2);
    float* s2b   = (float*)alloc(2ull * LP * 4);
    float* rnorm = (float*)alloc(2ull * LP * 4);
    float2* stat = (float2*)alloc(4096ull * 8);
    u16* A0      = (u16*)alloc(73728ull * 2);
    u16* A1      = (u16*)alloc(147456ull * 2);
    u16* A2      = (u16*)alloc(147456ull * 2);
    u16* A3      = (u16*)alloc(147456ull * 2);
    u16* A4      = (u16*)alloc(147456ull * 2);

    u16* patT    = (u16*)big1r;                      // convs
    u16* S0T     = (u16*)(big1r + 512);              // front-padded
    u16* gT      = (u16*)(big1r + 512);
    u16* scT     = (u16*)(big2r + 512);
    float* parts = (float*)big2r;

    const long h2bs = 128L * 4096;
    const long pMN = 128L * 4096;
    const long refbs = 128L * 7786;
    const long mbTbs = 4096L * 64, rmTbs = (long)LP * 64, baBS = 128L * LP;

    auto conv = [&](const float* src, const u16* W, int Cin, const float* bias,
                    const float* alpha, int act, const float* resid, float* dst) {
        int K = Cin * 9;
        d7_im2col<<<dim3((K + 255) / 256, 4096, 2), 256, 0, stream>>>(src, patT, Cin, (long)Cin * 4096, 4096L * K);
        d7_gemm<<<dim3(32, 6, 2), 256, 0, stream>>>(W, patT, 4096, K, K / 6, 1, 6,
            0, 4096L * K, nullptr, nullptr, 0, nullptr, 0,
            nullptr, 0, nullptr, 0, parts, pMN);
        d7_epi<<<dim3(2048, 1, 2), 256, 0, stream>>>(parts, 6, pMN, 6 * pMN,
            bias, alpha, act, resid, h2bs, 1.0f, dst, h2bs, (int)pMN);
    };

    d7_cast<<<dim3(288), 256, 0, stream>>>(bb0_w, A0, 73728);
    d7_cast<<<dim3(576), 256, 0, stream>>>(rb1_w1, A1, 147456);
    d7_cast<<<dim3(576), 256, 0, stream>>>(rb1_w2, A2, 147456);
    d7_cast<<<dim3(576), 256, 0, stream>>>(rb2_w1, A3, 147456);
    d7_cast<<<dim3(576), 256, 0, stream>>>(rb2_w2, A4, 147456);

    d7_maxpool<<<dim3(16, 64, 2), 256, 0, stream>>>(x, h0f);
    conv(h0f, A0, 64, bb0_b, bb0_a, 1, nullptr, h1f);
    conv(h1f, A1, 128, rb1_b1, nullptr, 2, nullptr, tbuf);
    conv(tbuf, A2, 128, rb1_b2, nullptr, 0, h1f, h2f);

    d7_resize<57><<<dim3(13, 128, 2), 256, 0, stream>>>(h2f, refb, refbs);
    d7_resize<51><<<dim3(11, 128, 2), 256, 0, stream>>>(h2f, refb + 3249L * 128, refbs);
    d7_resize<44><<<dim3(8, 128, 2), 256, 0, stream>>>(h2f, refb + 5850L * 128, refbs);

    // padded-layout 1x1 conv outputs (zero borders via memset)
    hipMemsetAsync(refmT, 0, 2ull * LP * 64 * 2, stream);
    hipMemsetAsync(baseA, 0, 2ull * 128 * LP * 2, stream);
    // mbT: identity mapping via HS=64,Wp=64,off=-65
    d7_c1T<<<dim3(16, 64, 2), 256, 0, stream>>>(h2f, h2bs, pamb_w, pamb_b, pamb_a, 4096, mbT, mbTbs, 64, 64, -65);
    d7_c1T<<<dim3(16, 64, 2), 256, 0, stream>>>(h2f, h2bs, pam_w, pam_b, pam_a, 4096, refmT, rmTbs, 64, 72, 0);
    d7_c1T<<<dim3(13, 64, 2), 256, 0, stream>>>(refb, refbs, pam_w, pam_b, pam_a, 3249, refmT, rmTbs, 57, 64, 4752);
    d7_c1T<<<dim3(11, 64, 2), 256, 0, stream>>>(refb + 3249L * 128, refbs, pam_w, pam_b, pam_a, 2601, refmT, rmTbs, 51, 56, 8528);
    d7_c1T<<<dim3(8, 64, 2), 256, 0, stream>>>(refb + 5850L * 128, refbs, pam_w, pam_b, pam_a, 1936, refmT, rmTbs, 44, 48, 11496);
    d7_c1N<<<dim3(16, 128, 2), 256, 0, stream>>>(h2f, h2bs, paa_w, paa_b, paa_a, 4096, baseA, baBS, 64, 72, 0);
    d7_c1N<<<dim3(13, 128, 2), 256, 0, stream>>>(refb, refbs, paa_w, paa_b, paa_a, 3249, baseA, baBS, 57, 64, 4752);
    d7_c1N<<<dim3(11, 128, 2), 256, 0, stream>>>(refb + 3249L * 128, refbs, paa_w, paa_b, paa_a, 2601, baseA, baBS, 51, 56, 8528);
    d7_c1N<<<dim3(8, 128, 2), 256, 0, stream>>>(refb + 5850L * 128, refbs, paa_w, paa_b, paa_a, 1936, baseA, baBS, 44, 48, 11496);

    d7_s2<<<dim3(54, 1, 2), 256, 0, stream>>>(refmT, s2b);
    d7_rnormk<<<dim3(54, 1, 2), 256, 0, stream>>>(s2b, rnorm);

    for (int b = 0; b < 2; ++b) {
        // S0T[p][l'] = sum_c mb[p][c]*refm[l'][c]
        d7_gemm<<<dim3(LP / 128, 32, 1), 256, 0, stream>>>(mbT + b * mbTbs, refmT + b * rmTbs,
            LP, 64, 64, 32, 1, 0, 0, nullptr, nullptr, 0, nullptr, 0,
            nullptr, 0, S0T, 0, nullptr, 0);
        d7_st1<<<dim3(7, 4096), 256, 0, stream>>>(S0T, scT, rnorm + b * LP);
        d7_stats<<<dim3(4096), 256, 0, stream>>>(scT, stat);
        d7_st2<<<dim3(7, 4096), 256, 0, stream>>>(scT, stat, rnorm + b * LP, gT);
        // out_pa = h2f + 0.25 * baseA · gT^T  (split-K = 12)
        d7_gemm<<<dim3(32, 12, 1), 256, 0, stream>>>(baseA + b * baBS, gT,
            4096, LP, LP / 12, 1, 12, 0, 0, nullptr, nullptr, 0, nullptr, 0,
            nullptr, 0, nullptr, 0, parts, pMN);
        d7_epi<<<dim3(2048, 1, 1), 256, 0, stream>>>(parts, 12, pMN, 0,
            nullptr, nullptr, 0, h2f + b * h2bs, 0, 0.25f, paf + b * h2bs, 0, (int)pMN);
    }

    conv(paf, A3, 128, rb2_b1, nullptr, 2, nullptr, tbuf);
    conv(tbuf, A4, 128, rb2_b2, nullptr, 0, paf, out);
}

// Round 6
// 1005.437 us; speedup vs baseline: 2.2148x; 1.0808x over previous
//
#include <hip/hip_runtime.h>

typedef unsigned short u16;
typedef __attribute__((ext_vector_type(8))) __bf16 bf16x8;
typedef __attribute__((ext_vector_type(8))) unsigned short ushort8;
typedef __attribute__((ext_vector_type(4))) float f32x4;

__device__ __forceinline__ float bf2f(u16 u) { return __uint_as_float(((unsigned)u) << 16); }
__device__ __forceinline__ u16 f2bf(float f) {
    unsigned x = __float_as_uint(f);
    x += 0x7fffu + ((x >> 16) & 1u);
    return (u16)(x >> 16);
}
__device__ __forceinline__ u16 f2h16(float f) {
    _Float16 h = (_Float16)f; u16 r; __builtin_memcpy(&r, &h, 2); return r;
}
__device__ __forceinline__ float h162f(u16 u) {
    _Float16 h; __builtin_memcpy(&h, &u, 2); return (float)h;
}

// Padded l-space: per-scale (HS+2) rows x W' cols with zero border, W' mult of 8.
// scale0: HS=64 W=72 off=0      (66*72=4752)
// scale1: HS=57 W=64 off=4752   (59*64=3776)
// scale2: HS=51 W=56 off=8528   (53*56=2968)
// scale3: HS=44 W=48 off=11496  (46*48=2208) -> 13704, dead zone to LP=13824
#define LP 13824

// ---------------------------------------------------------------------------
// GEMM: C[M,N] = A[M,K] * B[N,K]^T  (bf16 in, fp32 acc), 128x128 tile, BK=32.
// act: 1=prelu scalar alpha[0], 2=relu, 3=prelu per-row alpha[row].
// outputs: outP raw split-K partials | outF fp32 [M][N] | outB bf16 [M][N] |
//          outT bf16 transposed [N][ldT] via packed u64 (4 M-rows per store).
// ---------------------------------------------------------------------------
__global__ __launch_bounds__(256) void d7_gemm(
    const u16* __restrict__ A, const u16* __restrict__ B,
    int N, int K, int kLen, int mTiles, int S,
    long aBS, long bBS,
    const float* __restrict__ bias, const float* __restrict__ alpha, int act,
    const float* __restrict__ resid, long residBS,
    float* __restrict__ outF, long oFBS,
    u16* __restrict__ outB, long oBBS,
    u16* __restrict__ outT, int ldT, long oTBS,
    float* __restrict__ outP, long pMN)
{
    __shared__ u16 As[128 * 40];
    __shared__ u16 Bs[128 * 40];

    const int tid = threadIdx.x;
    const int wv = tid >> 6, lane = tid & 63;
    const int wm = wv >> 1, wn = wv & 1;
    const int bn = blockIdx.x;
    const int bm = blockIdx.y % mTiles;
    const int ks = blockIdx.y / mTiles;
    const int z  = blockIdx.z;
    const int kStart = ks * kLen;

    const int srow = tid >> 1;
    const int soff = (tid & 1) * 16;
    const u16* gA = A + z * aBS + (size_t)(bm * 128 + srow) * K + kStart + soff;
    const u16* gB = B + z * bBS + (size_t)(bn * 128 + srow) * K + kStart + soff;
    u16* lA = &As[srow * 40 + soff];
    u16* lB = &Bs[srow * 40 + soff];

    f32x4 acc[4][4] = {};

    for (int k0 = 0; k0 < kLen; k0 += 32) {
        __syncthreads();
        ((uint4*)lA)[0] = ((const uint4*)gA)[0];
        ((uint4*)lA)[1] = ((const uint4*)gA)[1];
        ((uint4*)lB)[0] = ((const uint4*)gB)[0];
        ((uint4*)lB)[1] = ((const uint4*)gB)[1];
        gA += 32; gB += 32;
        __syncthreads();

        bf16x8 a[4], b[4];
        #pragma unroll
        for (int mt = 0; mt < 4; ++mt)
            a[mt] = *reinterpret_cast<const bf16x8*>(&As[(wm * 64 + mt * 16 + (lane & 15)) * 40 + (lane >> 4) * 8]);
        #pragma unroll
        for (int nt = 0; nt < 4; ++nt)
            b[nt] = *reinterpret_cast<const bf16x8*>(&Bs[(wn * 64 + nt * 16 + (lane & 15)) * 40 + (lane >> 4) * 8]);
        #pragma unroll
        for (int mt = 0; mt < 4; ++mt)
            #pragma unroll
            for (int nt = 0; nt < 4; ++nt)
                acc[mt][nt] = __builtin_amdgcn_mfma_f32_16x16x32_bf16(a[mt], b[nt], acc[mt][nt], 0, 0, 0);
    }

    if (outP) {
        float* pp = outP + ((size_t)z * S + ks) * pMN;
        #pragma unroll
        for (int mt = 0; mt < 4; ++mt) {
            const int mg = bm * 128 + wm * 64 + mt * 16 + ((lane >> 4) << 2);
            #pragma unroll
            for (int nt = 0; nt < 4; ++nt) {
                const int ng = bn * 128 + wn * 64 + nt * 16 + (lane & 15);
                #pragma unroll
                for (int r = 0; r < 4; ++r)
                    pp[(size_t)(mg + r) * N + ng] = acc[mt][nt][r];
            }
        }
        return;
    }

    const float avalS = (act == 1) ? alpha[0] : 0.0f;
    #pragma unroll
    for (int mt = 0; mt < 4; ++mt) {
        const int mg = bm * 128 + wm * 64 + mt * 16 + ((lane >> 4) << 2);
        float bv[4] = {0.f, 0.f, 0.f, 0.f}, av[4];
        if (bias) {
            #pragma unroll
            for (int r = 0; r < 4; ++r) bv[r] = bias[mg + r];
        }
        if (act == 3) {
            #pragma unroll
            for (int r = 0; r < 4; ++r) av[r] = alpha[mg + r];
        }
        #pragma unroll
        for (int nt = 0; nt < 4; ++nt) {
            const int ng = bn * 128 + wn * 64 + nt * 16 + (lane & 15);
            float v[4];
            #pragma unroll
            for (int r = 0; r < 4; ++r) {
                float t = acc[mt][nt][r] + bv[r];
                if (act == 1) t = (t >= 0.f) ? t : avalS * t;
                else if (act == 2) t = fmaxf(t, 0.f);
                else if (act == 3) t = (t >= 0.f) ? t : av[r] * t;
                if (resid) t += resid[z * residBS + (size_t)(mg + r) * N + ng];
                v[r] = t;
            }
            if (outF) {
                #pragma unroll
                for (int r = 0; r < 4; ++r) outF[z * oFBS + (size_t)(mg + r) * N + ng] = v[r];
            }
            if (outB) {
                #pragma unroll
                for (int r = 0; r < 4; ++r) outB[z * oBBS + (size_t)(mg + r) * N + ng] = f2bf(v[r]);
            }
            if (outT) {
                unsigned long long pk = (unsigned long long)f2bf(v[0])
                    | ((unsigned long long)f2bf(v[1]) << 16)
                    | ((unsigned long long)f2bf(v[2]) << 32)
                    | ((unsigned long long)f2bf(v[3]) << 48);
                *reinterpret_cast<unsigned long long*>(outT + z * oTBS + (size_t)ng * ldT + mg) = pk;
            }
        }
    }
}

// split-K reduce + bias/act/resid epilogue; N fixed 4096 (m = i>>12)
__global__ __launch_bounds__(256) void d7_epi(
    const float* __restrict__ parts, int S, long sStride, long bStride,
    const float* __restrict__ bias, const float* __restrict__ alpha, int act,
    const float* __restrict__ resid, long residBS, float scale,
    float* __restrict__ out, long outBS, int total)
{
    int i = blockIdx.x * 256 + threadIdx.x;
    if (i >= total) return;
    int b = blockIdx.z;
    const float* p = parts + b * bStride + i;
    float s = 0.f;
    for (int t = 0; t < S; ++t) s += p[(size_t)t * sStride];
    s *= scale;
    if (bias) s += bias[i >> 12];
    if (act == 1) { float a = alpha[0]; s = (s >= 0.f) ? s : a * s; }
    else if (act == 2) s = fmaxf(s, 0.f);
    if (resid) s += resid[b * residBS + i];
    out[b * outBS + i] = s;
}

// ---------------------------------------------------------------------------
__global__ __launch_bounds__(256) void d7_cast(const float* __restrict__ src, u16* __restrict__ dst, int n) {
    int i = blockIdx.x * 256 + threadIdx.x;
    if (i < n) dst[i] = f2bf(src[i]);
}

// build concat weights/bias/alpha for the fused 1x1-conv GEMMs
__global__ __launch_bounds__(256) void d7_wbuild(
    const float* __restrict__ pamb_w, const float* __restrict__ pam_w, const float* __restrict__ paa_w,
    const float* __restrict__ pamb_b, const float* __restrict__ pam_b, const float* __restrict__ paa_b,
    const float* __restrict__ pamb_a, const float* __restrict__ pam_a, const float* __restrict__ paa_a,
    u16* __restrict__ W1, u16* __restrict__ W2,
    float* __restrict__ b1, float* __restrict__ a1,
    float* __restrict__ b2, float* __restrict__ a2)
{
    int i = blockIdx.x * 256 + threadIdx.x;
    if (i < 256 * 128) {
        int r = i >> 7, c = i & 127;
        float w1 = (r < 64) ? pamb_w[r * 128 + c] : (r < 128) ? pam_w[(r - 64) * 128 + c] : paa_w[(r - 128) * 128 + c];
        W1[i] = f2bf(w1);
        float w2 = (r < 64) ? pam_w[r * 128 + c] : (r < 192) ? paa_w[(r - 64) * 128 + c] : 0.f;
        W2[i] = f2bf(w2);
    }
    if (i < 256) {
        int r = i;
        b1[r] = (r < 64) ? pamb_b[r] : (r < 128) ? pam_b[r - 64] : paa_b[r - 128];
        a1[r] = (r < 64) ? pamb_a[0] : (r < 128) ? pam_a[0] : paa_a[0];
        b2[r] = (r < 64) ? pam_b[r] : (r < 192) ? paa_b[r - 64] : 0.f;
        a2[r] = (r < 64) ? pam_a[0] : (r < 192) ? paa_a[0] : 0.f;
    }
}

__global__ __launch_bounds__(256) void d7_maxpool(const float* __restrict__ x, float* __restrict__ out) {
    int p = blockIdx.x * 256 + threadIdx.x;
    int c = blockIdx.y, b = blockIdx.z;
    int oh = p >> 6, ow = p & 63;
    const float* ip = x + ((size_t)b * 64 + c) * 16384;
    float v0 = ip[(2 * oh) * 128 + 2 * ow];
    float v1 = ip[(2 * oh) * 128 + 2 * ow + 1];
    float v2 = ip[(2 * oh + 1) * 128 + 2 * ow];
    float v3 = ip[(2 * oh + 1) * 128 + 2 * ow + 1];
    out[((size_t)b * 64 + c) * 4096 + p] = fmaxf(fmaxf(v0, v1), fmaxf(v2, v3));
}

__global__ __launch_bounds__(256) void d7_im2col(const float* __restrict__ img, u16* __restrict__ patT,
                                                 int Cin, long inBS, long outBS) {
    int K = Cin * 9;
    int k = blockIdx.x * 256 + threadIdx.x;
    if (k >= K) return;
    int p = blockIdx.y, b = blockIdx.z;
    int c = k / 9, k9 = k - c * 9;
    int h = p >> 6, w = p & 63;
    int y = h + k9 / 3 - 1, x = w + (k9 % 3) - 1;
    const float* ip = img + b * inBS;
    float v = (y >= 0 && y < 64 && x >= 0 && x < 64) ? ip[(size_t)c * 4096 + y * 64 + x] : 0.f;
    patT[b * outBS + (size_t)p * K + k] = f2bf(v);
}

// transpose-cast: in fp32 [128][P] -> out bf16 [p][128] (rows p<P; pads pre-zeroed)
__global__ __launch_bounds__(256) void d7_t32(const float* __restrict__ in, long inBS, int P,
                                              u16* __restrict__ out, long outBS) {
    __shared__ float tile[32][33];
    int p0 = blockIdx.x * 32, c0 = blockIdx.y * 32, b = blockIdx.z;
    int tx = threadIdx.x & 31, ty = threadIdx.x >> 5;
    const float* ip = in + b * inBS;
    #pragma unroll
    for (int i = 0; i < 32; i += 8) {
        int c = c0 + ty + i, p = p0 + tx;
        tile[ty + i][tx] = (p < P) ? ip[(size_t)c * P + p] : 0.f;
    }
    __syncthreads();
    u16* op = out + b * outBS;
    #pragma unroll
    for (int i = 0; i < 32; i += 8) {
        int p = p0 + ty + i, c = c0 + tx;
        if (p < P) op[(size_t)p * 128 + c] = f2bf(tile[tx][ty + i]);
    }
}

// scatter K-major 64-wide rows: dst[l'(p)][0..63] = cT[pOff+p][colBase..colBase+63]
__global__ __launch_bounds__(256) void d7_scK(const u16* __restrict__ cT, long cBS, int ldC, int colBase,
                                              int pOff, int P, int HS, int Wp, int off,
                                              u16* __restrict__ dst, long dBS) {
    int t = blockIdx.x * 256 + threadIdx.x;
    int p = t >> 3, cg = t & 7;
    if (p >= P) return;
    int b = blockIdx.z;
    ushort8 v = *reinterpret_cast<const ushort8*>(cT + b * cBS + (size_t)(pOff + p) * ldC + colBase + cg * 8);
    int h = p / HS, w = p - h * HS;
    int lp = off + (h + 1) * Wp + w + 1;
    *reinterpret_cast<ushort8*>(dst + b * dBS + (size_t)lp * 64 + cg * 8) = v;
}

// scatter row-major: baseA[co][l'(p)] = cO[rowBase+co][pOff+p]
__global__ __launch_bounds__(256) void d7_scR(const u16* __restrict__ cO, long cBS, int ldC, int rowBase,
                                              int pOff, int P, int HS, int Wp, int off,
                                              u16* __restrict__ dst, long dBS) {
    int p = blockIdx.x * 256 + threadIdx.x;
    if (p >= P) return;
    int co = blockIdx.y, b = blockIdx.z;
    u16 v = cO[b * cBS + (size_t)(rowBase + co) * ldC + pOff + p];
    int h = p / HS, w = p - h * HS;
    int lp = off + (h + 1) * Wp + w + 1;
    dst[b * dBS + (size_t)co * LP + lp] = v;
}

// jax.image.resize bilinear antialias, 64 -> OS
template <int OS>
__device__ __forceinline__ void d7_taps(int o, int& i0, float w3[3]) {
    const float inv = 64.0f / OS;
    float s = (o + 0.5f) * inv - 0.5f;
    i0 = (int)ceilf(s - inv);
    float wsum = 0.f;
    #pragma unroll
    for (int t = 0; t < 3; ++t) {
        int y = i0 + t;
        float wt = 1.0f - fabsf((float)y - s) / inv;
        wt = (wt > 0.f && y >= 0 && y < 64) ? wt : 0.f;
        w3[t] = wt; wsum += wt;
    }
    float r = 1.0f / wsum;
    w3[0] *= r; w3[1] *= r; w3[2] *= r;
}

template <int OS>
__global__ __launch_bounds__(256) void d7_resize(const float* __restrict__ in, float* __restrict__ out, long out_bs) {
    int p = blockIdx.x * 256 + threadIdx.x;
    if (p >= OS * OS) return;
    int c = blockIdx.y, b = blockIdx.z;
    int oh = p / OS, ow = p - oh * OS;
    const float* img = in + ((size_t)b * 128 + c) * 4096;
    int y0, x0; float wy[3], wx[3];
    d7_taps<OS>(oh, y0, wy);
    d7_taps<OS>(ow, x0, wx);
    float sum = 0.f;
    #pragma unroll
    for (int iy = 0; iy < 3; ++iy) {
        if (wy[iy] <= 0.f) continue;
        float rs = 0.f;
        #pragma unroll
        for (int ix = 0; ix < 3; ++ix) {
            if (wx[ix] <= 0.f) continue;
            rs += wx[ix] * img[(y0 + iy) * 64 + (x0 + ix)];
        }
        sum += wy[iy] * rs;
    }
    out[(size_t)b * out_bs + (size_t)c * OS * OS + p] = sum;
}

__device__ __forceinline__ int d7_scaleW(int l) {
    return (l < 4752) ? 72 : (l < 8528) ? 64 : (l < 11496) ? 56 : 48;
}

// s2[l'] = sum_c refmT_pad[l'][c]^2
__global__ __launch_bounds__(256) void d7_s2(const u16* __restrict__ refmT, float* __restrict__ s2) {
    int l = blockIdx.x * 256 + threadIdx.x;
    if (l >= LP) return;
    int zb = blockIdx.z;
    const u16* r = refmT + (size_t)zb * LP * 64 + (size_t)l * 64;
    float s = 0.f;
    #pragma unroll
    for (int c8 = 0; c8 < 8; ++c8) {
        ushort8 v = *reinterpret_cast<const ushort8*>(r + c8 * 8);
        #pragma unroll
        for (int i = 0; i < 8; ++i) { float f = bf2f(v[i]); s += f * f; }
    }
    s2[zb * LP + l] = s;
}

// rnorm[l'] = interior ? 10/max(sqrt(9-tap sum of s2),1e-4) : 0   (softmax scale folded)
__global__ __launch_bounds__(256) void d7_rnormk(const float* __restrict__ s2, float* __restrict__ rnorm) {
    int l = blockIdx.x * 256 + threadIdx.x;
    if (l >= LP) return;
    int zb = blockIdx.z;
    int off, W, HS;
    if (l < 4752)       { off = 0;     W = 72; HS = 64; }
    else if (l < 8528)  { off = 4752;  W = 64; HS = 57; }
    else if (l < 11496) { off = 8528;  W = 56; HS = 51; }
    else                { off = 11496; W = 48; HS = 44; }
    int li = l - off, y = li / W, x = li - y * W;
    float v = 0.f;
    if (y >= 1 && y <= HS && x >= 1 && x <= HS) {
        const float* s = s2 + zb * LP;
        float a = 0.f;
        #pragma unroll
        for (int dy = -1; dy <= 1; ++dy)
            #pragma unroll
            for (int dx = -1; dx <= 1; ++dx)
                a += s[l + dy * W + dx];
        v = 10.f / fmaxf(sqrtf(a), 1e-4f);
    }
    rnorm[zb * LP + l] = v;
}

// stencil1: scT[p][l'] (fp16) = interior ? rnorm * sum_taps S0T : -1e4
__global__ __launch_bounds__(256) void d7_st1(const u16* __restrict__ in, u16* __restrict__ out,
                                              const float* __restrict__ rnorm) {
    int vg = blockIdx.x * 256 + threadIdx.x;
    if (vg >= LP / 8) return;
    int l8 = vg << 3;
    int p = blockIdx.y;
    int h = p >> 6, w = p & 63;
    int W = d7_scaleW(l8);
    float acc[8] = {0.f, 0.f, 0.f, 0.f, 0.f, 0.f, 0.f, 0.f};
    #pragma unroll
    for (int a = -1; a <= 1; ++a) {
        int ph = h + a;
        if ((unsigned)ph >= 64u) continue;
        #pragma unroll
        for (int b = -1; b <= 1; ++b) {
            int pw = w + b;
            if ((unsigned)pw >= 64u) continue;
            const u16* rp = in + (size_t)(p + a * 64 + b) * LP + l8 + a * W;
            ushort8 v = *reinterpret_cast<const ushort8*>(rp);
            if (b == 0) {
                #pragma unroll
                for (int i = 0; i < 8; ++i) acc[i] += bf2f(v[i]);
            } else if (b == -1) {
                acc[0] += bf2f(rp[-1]);
                #pragma unroll
                for (int i = 1; i < 8; ++i) acc[i] += bf2f(v[i - 1]);
            } else {
                acc[7] += bf2f(rp[8]);
                #pragma unroll
                for (int i = 0; i < 7; ++i) acc[i] += bf2f(v[i + 1]);
            }
        }
    }
    const float4 rn0 = *reinterpret_cast<const float4*>(rnorm + l8);
    const float4 rn1 = *reinterpret_cast<const float4*>(rnorm + l8 + 4);
    float rn[8] = {rn0.x, rn0.y, rn0.z, rn0.w, rn1.x, rn1.y, rn1.z, rn1.w};
    ushort8 res;
    #pragma unroll
    for (int i = 0; i < 8; ++i)
        res[i] = f2h16((rn[i] != 0.f) ? acc[i] * rn[i] : -1e4f);
    *reinterpret_cast<ushort8*>(out + (size_t)p * LP + l8) = res;
}

// per-row softmax stats on fp16 scores (already x10): stat[p] = (max, 1/Z)
__global__ __launch_bounds__(256) void d7_stats(const u16* __restrict__ sc, float2* __restrict__ stat) {
    int p = blockIdx.x, tid = threadIdx.x, wv = tid >> 6, lane = tid & 63;
    const u16* row = sc + (size_t)p * LP;
    float m = -3e38f;
    #pragma unroll
    for (int it = 0; it < 7; ++it) {
        int vg = tid + it * 256;
        if (vg < LP / 8) {
            ushort8 v = *reinterpret_cast<const ushort8*>(row + vg * 8);
            #pragma unroll
            for (int i = 0; i < 8; ++i) m = fmaxf(m, h162f(v[i]));
        }
    }
    #pragma unroll
    for (int o = 1; o < 64; o <<= 1) m = fmaxf(m, __shfl_xor(m, o));
    __shared__ float red[4];
    if (lane == 0) red[wv] = m;
    __syncthreads();
    m = fmaxf(fmaxf(red[0], red[1]), fmaxf(red[2], red[3]));
    __syncthreads();
    float s = 0.f;
    #pragma unroll
    for (int it = 0; it < 7; ++it) {
        int vg = tid + it * 256;
        if (vg < LP / 8) {
            ushort8 v = *reinterpret_cast<const ushort8*>(row + vg * 8);
            #pragma unroll
            for (int i = 0; i < 8; ++i) s += __expf(h162f(v[i]) - m);
        }
    }
    #pragma unroll
    for (int o = 1; o < 64; o <<= 1) s += __shfl_xor(s, o);
    if (lane == 0) red[wv] = s;
    __syncthreads();
    if (tid == 0) {
        float Z = red[0] + red[1] + red[2] + red[3];
        stat[p] = make_float2(m, 1.0f / Z);
    }
}

// stencil2: gT[p][l'] = interior ? sum_taps exp(v-m_r)*invZ_r : 0
__global__ __launch_bounds__(256) void d7_st2(const u16* __restrict__ in,
                                              const float2* __restrict__ stat,
                                              const float* __restrict__ rnorm,
                                              u16* __restrict__ out) {
    int vg = blockIdx.x * 256 + threadIdx.x;
    if (vg >= LP / 8) return;
    int l8 = vg << 3;
    int p = blockIdx.y;
    int h = p >> 6, w = p & 63;
    int W = d7_scaleW(l8);
    float acc[8] = {0.f, 0.f, 0.f, 0.f, 0.f, 0.f, 0.f, 0.f};
    #pragma unroll
    for (int a = -1; a <= 1; ++a) {
        int ph = h + a;
        if ((unsigned)ph >= 64u) continue;
        #pragma unroll
        for (int b = -1; b <= 1; ++b) {
            int pw = w + b;
            if ((unsigned)pw >= 64u) continue;
            int r = p + a * 64 + b;
            float2 st = stat[r];
            const u16* rp = in + (size_t)r * LP + l8 + a * W;
            ushort8 v = *reinterpret_cast<const ushort8*>(rp);
            if (b == 0) {
                #pragma unroll
                for (int i = 0; i < 8; ++i) acc[i] += __expf(h162f(v[i]) - st.x) * st.y;
            } else if (b == -1) {
                acc[0] += __expf(h162f(rp[-1]) - st.x) * st.y;
                #pragma unroll
                for (int i = 1; i < 8; ++i) acc[i] += __expf(h162f(v[i - 1]) - st.x) * st.y;
            } else {
                acc[7] += __expf(h162f(rp[8]) - st.x) * st.y;
                #pragma unroll
                for (int i = 0; i < 7; ++i) acc[i] += __expf(h162f(v[i + 1]) - st.x) * st.y;
            }
        }
    }
    const float4 rn0 = *reinterpret_cast<const float4*>(rnorm + l8);
    const float4 rn1 = *reinterpret_cast<const float4*>(rnorm + l8 + 4);
    float rn[8] = {rn0.x, rn0.y, rn0.z, rn0.w, rn1.x, rn1.y, rn1.z, rn1.w};
    ushort8 res;
    #pragma unroll
    for (int i = 0; i < 8; ++i)
        res[i] = f2bf((rn[i] != 0.f) ? acc[i] : 0.f);
    *reinterpret_cast<ushort8*>(out + (size_t)p * LP + l8) = res;
}

// ---------------------------------------------------------------------------
extern "C" void kernel_launch(void* const* d_in, const int* in_sizes, int n_in,
                              void* d_out, int out_size, void* d_ws, size_t ws_size,
                              hipStream_t stream) {
    const float* x      = (const float*)d_in[0];
    const float* bb0_w  = (const float*)d_in[1];
    const float* bb0_b  = (const float*)d_in[2];
    const float* bb0_a  = (const float*)d_in[3];
    const float* rb1_w1 = (const float*)d_in[4];
    const float* rb1_b1 = (const float*)d_in[5];
    const float* rb1_w2 = (const float*)d_in[6];
    const float* rb1_b2 = (const float*)d_in[7];
    const float* pamb_w = (const float*)d_in[8];
    const float* pamb_b = (const float*)d_in[9];
    const float* pamb_a = (const float*)d_in[10];
    const float* pam_w  = (const float*)d_in[11];
    const float* pam_b  = (const float*)d_in[12];
    const float* pam_a  = (const float*)d_in[13];
    const float* paa_w  = (const float*)d_in[14];
    const float* paa_b  = (const float*)d_in[15];
    const float* paa_a  = (const float*)d_in[16];
    const float* rb2_w1 = (const float*)d_in[17];
    const float* rb2_b1 = (const float*)d_in[18];
    const float* rb2_w2 = (const float*)d_in[19];
    const float* rb2_b2 = (const float*)d_in[20];
    float* out = (float*)d_out;
    (void)in_sizes; (void)n_in; (void)out_size; (void)ws_size;

    char* wp = (char*)d_ws;
    auto alloc = [&](size_t nbytes) { void* p = wp; wp += (nbytes + 255) & ~(size_t)255; return p; };
    const size_t BIG = 4096ull * LP * 2;             // 113 MB
    char* big1r  = (char*)alloc(BIG + 1024);
    char* big2r  = (char*)alloc(BIG + 1024);
    float* h0f   = (float*)alloc(2ull * 64 * 4096 * 4);
    float* h1f   = (float*)alloc(2ull * 128 * 4096 * 4);
    float* h2f   = (float*)alloc(2ull * 128 * 4096 * 4);
    float* paf   = (float*)alloc(2ull * 128 * 4096 * 4);
    float* tbuf  = (float*)alloc(2ull * 128 * 4096 * 4);
    u16* mbT     = (u16*)alloc(2ull * 4096 * 64 * 2);
    u16* refmT   = (u16*)alloc(2ull * LP * 64 * 2);
    u16* baseA   = (u16*)alloc(2ull * 128 * LP * 2);
    float* s2b   = (float*)alloc(2ull * LP * 4);
    float* rnorm = (float*)alloc(2ull * LP * 4);
    float2* stat = (float2*)alloc(4096ull * 8);
    u16* W1      = (u16*)alloc(256ull * 128 * 2);
    u16* W2      = (u16*)alloc(256ull * 128 * 2);
    float* b1v   = (float*)alloc(256 * 4);
    float* a1v   = (float*)alloc(256 * 4);
    float* b2v   = (float*)alloc(256 * 4);
    float* a2v   = (float*)alloc(256 * 4);
    u16* A0      = (u16*)alloc(73728ull * 2);
    u16* A1      = (u16*)alloc(147456ull * 2);
    u16* A2      = (u16*)alloc(147456ull * 2);
    u16* A3      = (u16*)alloc(147456ull * 2);
    u16* A4      = (u16*)alloc(147456ull * 2);
    // Views inside the big buffers (lifetime-disjoint phases):
    // big1: patT (convs) | h2T+refbT (1x1 prep) | S0T/gT (attention)
    u16* patT    = (u16*)big1r;
    u16* h2T     = (u16*)big1r;                          // [2][4096][128]  2 MB
    u16* refbT   = (u16*)(big1r + (4ull << 20));         // [2][7808][128]  4 MB
    u16* S0T     = (u16*)(big1r + 512);
    u16* gT      = (u16*)(big1r + 512);
    // big2: parts (convs/tconv) | cT1/cOut1/cT2/cOut2 + refb (1x1 prep) | scT (attention)
    float* parts = (float*)big2r;
    u16* cT1     = (u16*)big2r;                          // [2][4096][256]  4 MB
    u16* cOut1   = (u16*)(big2r + (4ull << 20));         // [2][256][4096]  4 MB
    u16* cT2     = (u16*)(big2r + (8ull << 20));         // [2][7808][256]  8 MB
    u16* cOut2   = (u16*)(big2r + (16ull << 20));        // [2][256][7808]  8 MB -> ends 24.8 MB
    float* refb  = (float*)(big2r + (26ull << 20));      // [2][level][128][OS^2] 8 MB -> ends 34 MB
    u16* scT     = (u16*)(big2r + 512);

    const long h2bs = 128L * 4096;
    const long pMN = 128L * 4096;
    const long refbs = 128L * 7786;
    const long mbTbs = 4096L * 64, rmTbs = (long)LP * 64, baBS = 128L * LP;
    const long cT1bs = 4096L * 256, cO1bs = 256L * 4096;
    const long cT2bs = 7808L * 256, cO2bs = 256L * 7808;
    const long rbTbs = 7808L * 128;

    auto conv = [&](const float* src, const u16* W, int Cin, const float* bias,
                    const float* alpha, int act, const float* resid, float* dst) {
        int K = Cin * 9;
        d7_im2col<<<dim3((K + 255) / 256, 4096, 2), 256, 0, stream>>>(src, patT, Cin, (long)Cin * 4096, 4096L * K);
        d7_gemm<<<dim3(32, 6, 2), 256, 0, stream>>>(W, patT, 4096, K, K / 6, 1, 6,
            0, 4096L * K, nullptr, nullptr, 0, nullptr, 0,
            nullptr, 0, nullptr, 0, nullptr, 0, 0, parts, pMN);
        d7_epi<<<dim3(2048, 1, 2), 256, 0, stream>>>(parts, 6, pMN, 6 * pMN,
            bias, alpha, act, resid, h2bs, 1.0f, dst, h2bs, (int)pMN);
    };

    d7_cast<<<dim3(288), 256, 0, stream>>>(bb0_w, A0, 73728);
    d7_cast<<<dim3(576), 256, 0, stream>>>(rb1_w1, A1, 147456);
    d7_cast<<<dim3(576), 256, 0, stream>>>(rb1_w2, A2, 147456);
    d7_cast<<<dim3(576), 256, 0, stream>>>(rb2_w1, A3, 147456);
    d7_cast<<<dim3(576), 256, 0, stream>>>(rb2_w2, A4, 147456);
    d7_wbuild<<<dim3(128), 256, 0, stream>>>(pamb_w, pam_w, paa_w, pamb_b, pam_b, paa_b,
                                             pamb_a, pam_a, paa_a, W1, W2, b1v, a1v, b2v, a2v);

    d7_maxpool<<<dim3(16, 64, 2), 256, 0, stream>>>(x, h0f);
    conv(h0f, A0, 64, bb0_b, bb0_a, 1, nullptr, h1f);
    conv(h1f, A1, 128, rb1_b1, nullptr, 2, nullptr, tbuf);
    conv(tbuf, A2, 128, rb1_b2, nullptr, 0, h1f, h2f);

    d7_resize<57><<<dim3(13, 128, 2), 256, 0, stream>>>(h2f, refb, refbs);
    d7_resize<51><<<dim3(11, 128, 2), 256, 0, stream>>>(h2f, refb + 3249L * 128, refbs);
    d7_resize<44><<<dim3(8, 128, 2), 256, 0, stream>>>(h2f, refb + 5850L * 128, refbs);

    // p-major bf16 operands for the fused 1x1-conv GEMMs.
    // NOTE: refb is LEVEL-major per batch ([level][128][OS^2]) — transpose each
    // level separately into the row-concatenated refbT (R5 bug: one t32 over
    // the whole buffer assumed [128][7786] and scrambled levels 1-3).
    hipMemsetAsync(refbT, 0, 2ull * rbTbs * 2, stream);
    d7_t32<<<dim3(128, 4, 2), 256, 0, stream>>>(h2f, h2bs, 4096, h2T, 4096L * 128);
    d7_t32<<<dim3(102, 4, 2), 256, 0, stream>>>(refb, refbs, 3249, refbT, rbTbs);
    d7_t32<<<dim3(82, 4, 2), 256, 0, stream>>>(refb + 3249L * 128, refbs, 2601, refbT + 3249L * 128, rbTbs);
    d7_t32<<<dim3(61, 4, 2), 256, 0, stream>>>(refb + 5850L * 128, refbs, 1936, refbT + 5850L * 128, rbTbs);

    // all 1x1 convs as two GEMMs (per-row-alpha prelu), row-major + transposed outputs
    d7_gemm<<<dim3(32, 2, 2), 256, 0, stream>>>(W1, h2T, 4096, 128, 128, 2, 1,
        0, 4096L * 128, b1v, a1v, 3, nullptr, 0,
        nullptr, 0, cOut1, cO1bs, cT1, 256, cT1bs, nullptr, 0);
    d7_gemm<<<dim3(61, 2, 2), 256, 0, stream>>>(W2, refbT, 7808, 128, 128, 2, 1,
        0, rbTbs, b2v, a2v, 3, nullptr, 0,
        nullptr, 0, cOut2, cO2bs, cT2, 256, cT2bs, nullptr, 0);

    // scatter into padded attention layouts
    hipMemsetAsync(refmT, 0, 2ull * LP * 64 * 2, stream);
    hipMemsetAsync(baseA, 0, 2ull * 128 * LP * 2, stream);
    d7_scK<<<dim3(128, 1, 2), 256, 0, stream>>>(cT1, cT1bs, 256, 0, 0, 4096, 64, 64, -65, mbT, mbTbs);
    d7_scK<<<dim3(128, 1, 2), 256, 0, stream>>>(cT1, cT1bs, 256, 64, 0, 4096, 64, 72, 0, refmT, rmTbs);
    d7_scK<<<dim3(102, 1, 2), 256, 0, stream>>>(cT2, cT2bs, 256, 0, 0, 3249, 57, 64, 4752, refmT, rmTbs);
    d7_scK<<<dim3(82, 1, 2), 256, 0, stream>>>(cT2, cT2bs, 256, 0, 3249, 2601, 51, 56, 8528, refmT, rmTbs);
    d7_scK<<<dim3(61, 1, 2), 256, 0, stream>>>(cT2, cT2bs, 256, 0, 5850, 1936, 44, 48, 11496, refmT, rmTbs);
    d7_scR<<<dim3(16, 128, 2), 256, 0, stream>>>(cOut1, cO1bs, 4096, 128, 0, 4096, 64, 72, 0, baseA, baBS);
    d7_scR<<<dim3(13, 128, 2), 256, 0, stream>>>(cOut2, cO2bs, 7808, 64, 0, 3249, 57, 64, 4752, baseA, baBS);
    d7_scR<<<dim3(11, 128, 2), 256, 0, stream>>>(cOut2, cO2bs, 7808, 64, 3249, 2601, 51, 56, 8528, baseA, baBS);
    d7_scR<<<dim3(8, 128, 2), 256, 0, stream>>>(cOut2, cO2bs, 7808, 64, 5850, 1936, 44, 48, 11496, baseA, baBS);

    d7_s2<<<dim3(54, 1, 2), 256, 0, stream>>>(refmT, s2b);
    d7_rnormk<<<dim3(54, 1, 2), 256, 0, stream>>>(s2b, rnorm);

    for (int b = 0; b < 2; ++b) {
        // S0T[p][l'] via transposed 8B stores: A=refmT (M=LP), B=mbT (N=4096)
        d7_gemm<<<dim3(32, 108, 1), 256, 0, stream>>>(refmT + b * rmTbs, mbT + b * mbTbs,
            4096, 64, 64, 108, 1, 0, 0, nullptr, nullptr, 0, nullptr, 0,
            nullptr, 0, nullptr, 0, S0T, LP, 0, nullptr, 0);
        d7_st1<<<dim3(7, 4096), 256, 0, stream>>>(S0T, scT, rnorm + b * LP);
        d7_stats<<<dim3(4096), 256, 0, stream>>>(scT, stat);
        d7_st2<<<dim3(7, 4096), 256, 0, stream>>>(scT, stat, rnorm + b * LP, gT);
        d7_gemm<<<dim3(32, 12, 1), 256, 0, stream>>>(baseA + b * baBS, gT,
            4096, LP, LP / 12, 1, 12, 0, 0, nullptr, nullptr, 0, nullptr, 0,
            nullptr, 0, nullptr, 0, nullptr, 0, 0, parts, pMN);
        d7_epi<<<dim3(2048, 1, 1), 256, 0, stream>>>(parts, 12, pMN, 0,
            nullptr, nullptr, 0, h2f + b * h2bs, 0, 0.25f, paf + b * h2bs, 0, (int)pMN);
    }

    conv(paf, A3, 128, rb2_b1, nullptr, 2, nullptr, tbuf);
    conv(tbuf, A4, 128, rb2_b2, nullptr, 0, paf, out);
}

// Round 7
// 993.523 us; speedup vs baseline: 2.2414x; 1.0120x over previous
//
#include <hip/hip_runtime.h>

typedef unsigned short u16;
typedef __attribute__((ext_vector_type(8))) __bf16 bf16x8;
typedef __attribute__((ext_vector_type(8))) unsigned short ushort8;
typedef __attribute__((ext_vector_type(4))) float f32x4;

__device__ __forceinline__ float bf2f(u16 u) { return __uint_as_float(((unsigned)u) << 16); }
__device__ __forceinline__ u16 f2bf(float f) {
    unsigned x = __float_as_uint(f);
    x += 0x7fffu + ((x >> 16) & 1u);
    return (u16)(x >> 16);
}
__device__ __forceinline__ u16 f2h16(float f) {
    _Float16 h = (_Float16)f; u16 r; __builtin_memcpy(&r, &h, 2); return r;
}
__device__ __forceinline__ float h162f(u16 u) {
    _Float16 h; __builtin_memcpy(&h, &u, 2); return (float)h;
}

// Padded l-space: per-scale (HS+2) rows x W' cols with zero border, W' mult of 8.
// scale0: HS=64 W=72 off=0      (66*72=4752)
// scale1: HS=57 W=64 off=4752   (59*64=3776)
// scale2: HS=51 W=56 off=8528   (53*56=2968)
// scale3: HS=44 W=48 off=11496  (46*48=2208) -> 13704, dead zone to LP=13824
#define LP 13824

// ---------------------------------------------------------------------------
// GEMM: C[M,N] = A[M,K] * B[N,K]^T  (bf16 in, fp32 acc), 128x128 tile, BK=32.
// act: 1=prelu scalar alpha[0], 2=relu, 3=prelu per-row alpha[row].
// outputs: outP split-K partials (fp32, or bf16 if pBf) | outF fp32 | outB bf16 |
//          outT bf16 transposed [N][ldT] via packed u64.
// ---------------------------------------------------------------------------
__global__ __launch_bounds__(256) void d7_gemm(
    const u16* __restrict__ A, const u16* __restrict__ B,
    int N, int K, int kLen, int mTiles, int S,
    long aBS, long bBS,
    const float* __restrict__ bias, const float* __restrict__ alpha, int act,
    const float* __restrict__ resid, long residBS,
    float* __restrict__ outF, long oFBS,
    u16* __restrict__ outB, long oBBS,
    u16* __restrict__ outT, int ldT, long oTBS,
    float* __restrict__ outP, long pMN, int pBf)
{
    __shared__ u16 As[128 * 40];
    __shared__ u16 Bs[128 * 40];

    const int tid = threadIdx.x;
    const int wv = tid >> 6, lane = tid & 63;
    const int wm = wv >> 1, wn = wv & 1;
    const int bn = blockIdx.x;
    const int bm = blockIdx.y % mTiles;
    const int ks = blockIdx.y / mTiles;
    const int z  = blockIdx.z;
    const int kStart = ks * kLen;

    const int srow = tid >> 1;
    const int soff = (tid & 1) * 16;
    const u16* gA = A + z * aBS + (size_t)(bm * 128 + srow) * K + kStart + soff;
    const u16* gB = B + z * bBS + (size_t)(bn * 128 + srow) * K + kStart + soff;
    u16* lA = &As[srow * 40 + soff];
    u16* lB = &Bs[srow * 40 + soff];

    f32x4 acc[4][4] = {};

    for (int k0 = 0; k0 < kLen; k0 += 32) {
        __syncthreads();
        ((uint4*)lA)[0] = ((const uint4*)gA)[0];
        ((uint4*)lA)[1] = ((const uint4*)gA)[1];
        ((uint4*)lB)[0] = ((const uint4*)gB)[0];
        ((uint4*)lB)[1] = ((const uint4*)gB)[1];
        gA += 32; gB += 32;
        __syncthreads();

        bf16x8 a[4], b[4];
        #pragma unroll
        for (int mt = 0; mt < 4; ++mt)
            a[mt] = *reinterpret_cast<const bf16x8*>(&As[(wm * 64 + mt * 16 + (lane & 15)) * 40 + (lane >> 4) * 8]);
        #pragma unroll
        for (int nt = 0; nt < 4; ++nt)
            b[nt] = *reinterpret_cast<const bf16x8*>(&Bs[(wn * 64 + nt * 16 + (lane & 15)) * 40 + (lane >> 4) * 8]);
        #pragma unroll
        for (int mt = 0; mt < 4; ++mt)
            #pragma unroll
            for (int nt = 0; nt < 4; ++nt)
                acc[mt][nt] = __builtin_amdgcn_mfma_f32_16x16x32_bf16(a[mt], b[nt], acc[mt][nt], 0, 0, 0);
    }

    if (outP) {
        const size_t pbase = ((size_t)z * S + ks) * pMN;
        #pragma unroll
        for (int mt = 0; mt < 4; ++mt) {
            const int mg = bm * 128 + wm * 64 + mt * 16 + ((lane >> 4) << 2);
            #pragma unroll
            for (int nt = 0; nt < 4; ++nt) {
                const int ng = bn * 128 + wn * 64 + nt * 16 + (lane & 15);
                if (pBf) {
                    u16* pp = (u16*)outP + pbase;
                    #pragma unroll
                    for (int r = 0; r < 4; ++r)
                        pp[(size_t)(mg + r) * N + ng] = f2bf(acc[mt][nt][r]);
                } else {
                    float* pp = outP + pbase;
                    #pragma unroll
                    for (int r = 0; r < 4; ++r)
                        pp[(size_t)(mg + r) * N + ng] = acc[mt][nt][r];
                }
            }
        }
        return;
    }

    const float avalS = (act == 1) ? alpha[0] : 0.0f;
    #pragma unroll
    for (int mt = 0; mt < 4; ++mt) {
        const int mg = bm * 128 + wm * 64 + mt * 16 + ((lane >> 4) << 2);
        float bv[4] = {0.f, 0.f, 0.f, 0.f}, av[4];
        if (bias) {
            #pragma unroll
            for (int r = 0; r < 4; ++r) bv[r] = bias[mg + r];
        }
        if (act == 3) {
            #pragma unroll
            for (int r = 0; r < 4; ++r) av[r] = alpha[mg + r];
        }
        #pragma unroll
        for (int nt = 0; nt < 4; ++nt) {
            const int ng = bn * 128 + wn * 64 + nt * 16 + (lane & 15);
            float v[4];
            #pragma unroll
            for (int r = 0; r < 4; ++r) {
                float t = acc[mt][nt][r] + bv[r];
                if (act == 1) t = (t >= 0.f) ? t : avalS * t;
                else if (act == 2) t = fmaxf(t, 0.f);
                else if (act == 3) t = (t >= 0.f) ? t : av[r] * t;
                if (resid) t += resid[z * residBS + (size_t)(mg + r) * N + ng];
                v[r] = t;
            }
            if (outF) {
                #pragma unroll
                for (int r = 0; r < 4; ++r) outF[z * oFBS + (size_t)(mg + r) * N + ng] = v[r];
            }
            if (outB) {
                #pragma unroll
                for (int r = 0; r < 4; ++r) outB[z * oBBS + (size_t)(mg + r) * N + ng] = f2bf(v[r]);
            }
            if (outT) {
                unsigned long long pk = (unsigned long long)f2bf(v[0])
                    | ((unsigned long long)f2bf(v[1]) << 16)
                    | ((unsigned long long)f2bf(v[2]) << 32)
                    | ((unsigned long long)f2bf(v[3]) << 48);
                *reinterpret_cast<unsigned long long*>(outT + z * oTBS + (size_t)ng * ldT + mg) = pk;
            }
        }
    }
}

// split-K reduce + bias/act/resid epilogue; N fixed 4096 (m = i>>12)
__global__ __launch_bounds__(256) void d7_epi(
    const void* __restrict__ parts, int S, long sStride, long bStride,
    const float* __restrict__ bias, const float* __restrict__ alpha, int act,
    const float* __restrict__ resid, long residBS, float scale,
    float* __restrict__ out, long outBS, int total, int pBf)
{
    int i = blockIdx.x * 256 + threadIdx.x;
    if (i >= total) return;
    int b = blockIdx.z;
    float s = 0.f;
    if (pBf) {
        const u16* p = (const u16*)parts + b * bStride + i;
        for (int t = 0; t < S; ++t) s += bf2f(p[(size_t)t * sStride]);
    } else {
        const float* p = (const float*)parts + b * bStride + i;
        for (int t = 0; t < S; ++t) s += p[(size_t)t * sStride];
    }
    s *= scale;
    if (bias) s += bias[i >> 12];
    if (act == 1) { float a = alpha[0]; s = (s >= 0.f) ? s : a * s; }
    else if (act == 2) s = fmaxf(s, 0.f);
    if (resid) s += resid[b * residBS + i];
    out[b * outBS + i] = s;
}

// ---------------------------------------------------------------------------
__global__ __launch_bounds__(256) void d7_cast(const float* __restrict__ src, u16* __restrict__ dst, int n) {
    int i = blockIdx.x * 256 + threadIdx.x;
    if (i < n) dst[i] = f2bf(src[i]);
}

// build concat weights/bias/alpha for the fused 1x1-conv GEMMs
__global__ __launch_bounds__(256) void d7_wbuild(
    const float* __restrict__ pamb_w, const float* __restrict__ pam_w, const float* __restrict__ paa_w,
    const float* __restrict__ pamb_b, const float* __restrict__ pam_b, const float* __restrict__ paa_b,
    const float* __restrict__ pamb_a, const float* __restrict__ pam_a, const float* __restrict__ paa_a,
    u16* __restrict__ W1, u16* __restrict__ W2,
    float* __restrict__ b1, float* __restrict__ a1,
    float* __restrict__ b2, float* __restrict__ a2)
{
    int i = blockIdx.x * 256 + threadIdx.x;
    if (i < 256 * 128) {
        int r = i >> 7, c = i & 127;
        float w1 = (r < 64) ? pamb_w[r * 128 + c] : (r < 128) ? pam_w[(r - 64) * 128 + c] : paa_w[(r - 128) * 128 + c];
        W1[i] = f2bf(w1);
        float w2 = (r < 64) ? pam_w[r * 128 + c] : (r < 192) ? paa_w[(r - 64) * 128 + c] : 0.f;
        W2[i] = f2bf(w2);
    }
    if (i < 256) {
        int r = i;
        b1[r] = (r < 64) ? pamb_b[r] : (r < 128) ? pam_b[r - 64] : paa_b[r - 128];
        a1[r] = (r < 64) ? pamb_a[0] : (r < 128) ? pam_a[0] : paa_a[0];
        b2[r] = (r < 64) ? pam_b[r] : (r < 192) ? paa_b[r - 64] : 0.f;
        a2[r] = (r < 64) ? pam_a[0] : (r < 192) ? paa_a[0] : 0.f;
    }
}

__global__ __launch_bounds__(256) void d7_maxpool(const float* __restrict__ x, float* __restrict__ out) {
    int p = blockIdx.x * 256 + threadIdx.x;
    int c = blockIdx.y, b = blockIdx.z;
    int oh = p >> 6, ow = p & 63;
    const float* ip = x + ((size_t)b * 64 + c) * 16384;
    float v0 = ip[(2 * oh) * 128 + 2 * ow];
    float v1 = ip[(2 * oh) * 128 + 2 * ow + 1];
    float v2 = ip[(2 * oh + 1) * 128 + 2 * ow];
    float v3 = ip[(2 * oh + 1) * 128 + 2 * ow + 1];
    out[((size_t)b * 64 + c) * 4096 + p] = fmaxf(fmaxf(v0, v1), fmaxf(v2, v3));
}

__global__ __launch_bounds__(256) void d7_im2col(const float* __restrict__ img, u16* __restrict__ patT,
                                                 int Cin, long inBS, long outBS) {
    int K = Cin * 9;
    int k = blockIdx.x * 256 + threadIdx.x;
    if (k >= K) return;
    int p = blockIdx.y, b = blockIdx.z;
    int c = k / 9, k9 = k - c * 9;
    int h = p >> 6, w = p & 63;
    int y = h + k9 / 3 - 1, x = w + (k9 % 3) - 1;
    const float* ip = img + b * inBS;
    float v = (y >= 0 && y < 64 && x >= 0 && x < 64) ? ip[(size_t)c * 4096 + y * 64 + x] : 0.f;
    patT[b * outBS + (size_t)p * K + k] = f2bf(v);
}

// transpose-cast: in fp32 [128][P] -> out bf16 [p][128] (rows p<P; pads pre-zeroed)
__global__ __launch_bounds__(256) void d7_t32(const float* __restrict__ in, long inBS, int P,
                                              u16* __restrict__ out, long outBS) {
    __shared__ float tile[32][33];
    int p0 = blockIdx.x * 32, c0 = blockIdx.y * 32, b = blockIdx.z;
    int tx = threadIdx.x & 31, ty = threadIdx.x >> 5;
    const float* ip = in + b * inBS;
    #pragma unroll
    for (int i = 0; i < 32; i += 8) {
        int c = c0 + ty + i, p = p0 + tx;
        tile[ty + i][tx] = (p < P) ? ip[(size_t)c * P + p] : 0.f;
    }
    __syncthreads();
    u16* op = out + b * outBS;
    #pragma unroll
    for (int i = 0; i < 32; i += 8) {
        int p = p0 + ty + i, c = c0 + tx;
        if (p < P) op[(size_t)p * 128 + c] = f2bf(tile[tx][ty + i]);
    }
}

// scatter K-major 64-wide rows: dst[l'(p)][0..63] = cT[pOff+p][colBase..colBase+63]
// optional: s2out[l'] = sum over 64 channels of v^2 (8-lane shfl reduce)
__global__ __launch_bounds__(256) void d7_scK(const u16* __restrict__ cT, long cBS, int ldC, int colBase,
                                              int pOff, int P, int HS, int Wp, int off,
                                              u16* __restrict__ dst, long dBS,
                                              float* __restrict__ s2out) {
    int t = blockIdx.x * 256 + threadIdx.x;
    int p = t >> 3, cg = t & 7;
    if (p >= P) return;
    int b = blockIdx.z;
    ushort8 v = *reinterpret_cast<const ushort8*>(cT + b * cBS + (size_t)(pOff + p) * ldC + colBase + cg * 8);
    int h = p / HS, w = p - h * HS;
    int lp = off + (h + 1) * Wp + w + 1;
    *reinterpret_cast<ushort8*>(dst + b * dBS + (size_t)lp * 64 + cg * 8) = v;
    if (s2out) {
        float ss = 0.f;
        #pragma unroll
        for (int i = 0; i < 8; ++i) { float f = bf2f(v[i]); ss += f * f; }
        ss += __shfl_xor(ss, 1);
        ss += __shfl_xor(ss, 2);
        ss += __shfl_xor(ss, 4);
        if (cg == 0) s2out[(size_t)b * LP + lp] = ss;
    }
}

// scatter row-major: baseA[co][l'(p)] = cO[rowBase+co][pOff+p]
__global__ __launch_bounds__(256) void d7_scR(const u16* __restrict__ cO, long cBS, int ldC, int rowBase,
                                              int pOff, int P, int HS, int Wp, int off,
                                              u16* __restrict__ dst, long dBS) {
    int p = blockIdx.x * 256 + threadIdx.x;
    if (p >= P) return;
    int co = blockIdx.y, b = blockIdx.z;
    u16 v = cO[b * cBS + (size_t)(rowBase + co) * ldC + pOff + p];
    int h = p / HS, w = p - h * HS;
    int lp = off + (h + 1) * Wp + w + 1;
    dst[b * dBS + (size_t)co * LP + lp] = v;
}

// jax.image.resize bilinear antialias, 64 -> OS
template <int OS>
__device__ __forceinline__ void d7_taps(int o, int& i0, float w3[3]) {
    const float inv = 64.0f / OS;
    float s = (o + 0.5f) * inv - 0.5f;
    i0 = (int)ceilf(s - inv);
    float wsum = 0.f;
    #pragma unroll
    for (int t = 0; t < 3; ++t) {
        int y = i0 + t;
        float wt = 1.0f - fabsf((float)y - s) / inv;
        wt = (wt > 0.f && y >= 0 && y < 64) ? wt : 0.f;
        w3[t] = wt; wsum += wt;
    }
    float r = 1.0f / wsum;
    w3[0] *= r; w3[1] *= r; w3[2] *= r;
}

template <int OS>
__global__ __launch_bounds__(256) void d7_resize(const float* __restrict__ in, float* __restrict__ out, long out_bs) {
    int p = blockIdx.x * 256 + threadIdx.x;
    if (p >= OS * OS) return;
    int c = blockIdx.y, b = blockIdx.z;
    int oh = p / OS, ow = p - oh * OS;
    const float* img = in + ((size_t)b * 128 + c) * 4096;
    int y0, x0; float wy[3], wx[3];
    d7_taps<OS>(oh, y0, wy);
    d7_taps<OS>(ow, x0, wx);
    float sum = 0.f;
    #pragma unroll
    for (int iy = 0; iy < 3; ++iy) {
        if (wy[iy] <= 0.f) continue;
        float rs = 0.f;
        #pragma unroll
        for (int ix = 0; ix < 3; ++ix) {
            if (wx[ix] <= 0.f) continue;
            rs += wx[ix] * img[(y0 + iy) * 64 + (x0 + ix)];
        }
        sum += wy[iy] * rs;
    }
    out[(size_t)b * out_bs + (size_t)c * OS * OS + p] = sum;
}

__device__ __forceinline__ int d7_scaleW(int l) {
    return (l < 4752) ? 72 : (l < 8528) ? 64 : (l < 11496) ? 56 : 48;
}

// rnorm[l'] = interior ? (10*log2e)/max(sqrt(9-tap sum of s2),1e-4) : 0
// (softmax scale AND log2-domain conversion folded in)
__global__ __launch_bounds__(256) void d7_rnormk(const float* __restrict__ s2, float* __restrict__ rnorm) {
    int l = blockIdx.x * 256 + threadIdx.x;
    if (l >= LP) return;
    int zb = blockIdx.z;
    int off, W, HS;
    if (l < 4752)       { off = 0;     W = 72; HS = 64; }
    else if (l < 8528)  { off = 4752;  W = 64; HS = 57; }
    else if (l < 11496) { off = 8528;  W = 56; HS = 51; }
    else                { off = 11496; W = 48; HS = 44; }
    int li = l - off, y = li / W, x = li - y * W;
    float v = 0.f;
    if (y >= 1 && y <= HS && x >= 1 && x <= HS) {
        const float* s = s2 + (size_t)zb * LP;
        float a = 0.f;
        #pragma unroll
        for (int dy = -1; dy <= 1; ++dy)
            #pragma unroll
            for (int dx = -1; dx <= 1; ++dx)
                a += s[l + dy * W + dx];
        v = 14.426950408889634f / fmaxf(sqrtf(a), 1e-4f);
    }
    rnorm[(size_t)zb * LP + l] = v;
}

// stencil1: scT[p][l'] (fp16, log2-domain) = interior ? rnorm * sum_taps S0T : -1e4
__global__ __launch_bounds__(256) void d7_st1(const u16* __restrict__ in, u16* __restrict__ out,
                                              const float* __restrict__ rnorm) {
    int vg = blockIdx.x * 256 + threadIdx.x;
    if (vg >= LP / 8) return;
    int l8 = vg << 3;
    int p = blockIdx.y;
    int h = p >> 6, w = p & 63;
    int W = d7_scaleW(l8);
    float acc[8] = {0.f, 0.f, 0.f, 0.f, 0.f, 0.f, 0.f, 0.f};
    #pragma unroll
    for (int a = -1; a <= 1; ++a) {
        int ph = h + a;
        if ((unsigned)ph >= 64u) continue;
        #pragma unroll
        for (int b = -1; b <= 1; ++b) {
            int pw = w + b;
            if ((unsigned)pw >= 64u) continue;
            const u16* rp = in + (size_t)(p + a * 64 + b) * LP + l8 + a * W;
            ushort8 v = *reinterpret_cast<const ushort8*>(rp);
            if (b == 0) {
                #pragma unroll
                for (int i = 0; i < 8; ++i) acc[i] += bf2f(v[i]);
            } else if (b == -1) {
                acc[0] += bf2f(rp[-1]);
                #pragma unroll
                for (int i = 1; i < 8; ++i) acc[i] += bf2f(v[i - 1]);
            } else {
                acc[7] += bf2f(rp[8]);
                #pragma unroll
                for (int i = 0; i < 7; ++i) acc[i] += bf2f(v[i + 1]);
            }
        }
    }
    const float4 rn0 = *reinterpret_cast<const float4*>(rnorm + l8);
    const float4 rn1 = *reinterpret_cast<const float4*>(rnorm + l8 + 4);
    float rn[8] = {rn0.x, rn0.y, rn0.z, rn0.w, rn1.x, rn1.y, rn1.z, rn1.w};
    ushort8 res;
    #pragma unroll
    for (int i = 0; i < 8; ++i)
        res[i] = f2h16((rn[i] != 0.f) ? acc[i] * rn[i] : -1e4f);
    *reinterpret_cast<ushort8*>(out + (size_t)p * LP + l8) = res;
}

// per-row softmax stat (log2 domain): statM[p] = m + log2(Z), Z = sum exp2(v-m)
__global__ __launch_bounds__(256) void d7_stats(const u16* __restrict__ sc, float* __restrict__ statM) {
    int p = blockIdx.x, tid = threadIdx.x, wv = tid >> 6, lane = tid & 63;
    const u16* row = sc + (size_t)p * LP;
    float m = -3e38f;
    #pragma unroll
    for (int it = 0; it < 7; ++it) {
        int vg = tid + it * 256;
        if (vg < LP / 8) {
            ushort8 v = *reinterpret_cast<const ushort8*>(row + vg * 8);
            #pragma unroll
            for (int i = 0; i < 8; ++i) m = fmaxf(m, h162f(v[i]));
        }
    }
    #pragma unroll
    for (int o = 1; o < 64; o <<= 1) m = fmaxf(m, __shfl_xor(m, o));
    __shared__ float red[4];
    if (lane == 0) red[wv] = m;
    __syncthreads();
    m = fmaxf(fmaxf(red[0], red[1]), fmaxf(red[2], red[3]));
    __syncthreads();
    float s = 0.f;
    #pragma unroll
    for (int it = 0; it < 7; ++it) {
        int vg = tid + it * 256;
        if (vg < LP / 8) {
            ushort8 v = *reinterpret_cast<const ushort8*>(row + vg * 8);
            #pragma unroll
            for (int i = 0; i < 8; ++i) s += __builtin_amdgcn_exp2f(h162f(v[i]) - m);
        }
    }
    #pragma unroll
    for (int o = 1; o < 64; o <<= 1) s += __shfl_xor(s, o);
    if (lane == 0) red[wv] = s;
    __syncthreads();
    if (tid == 0) {
        float Z = red[0] + red[1] + red[2] + red[3];
        statM[p] = m + __log2f(Z);
    }
}

// stencil2: gT[p][l'] = interior ? sum_taps exp2(v - M'_r) : 0
__global__ __launch_bounds__(256) void d7_st2(const u16* __restrict__ in,
                                              const float* __restrict__ statM,
                                              const float* __restrict__ rnorm,
                                              u16* __restrict__ out) {
    int vg = blockIdx.x * 256 + threadIdx.x;
    if (vg >= LP / 8) return;
    int l8 = vg << 3;
    int p = blockIdx.y;
    int h = p >> 6, w = p & 63;
    int W = d7_scaleW(l8);
    float acc[8] = {0.f, 0.f, 0.f, 0.f, 0.f, 0.f, 0.f, 0.f};
    #pragma unroll
    for (int a = -1; a <= 1; ++a) {
        int ph = h + a;
        if ((unsigned)ph >= 64u) continue;
        #pragma unroll
        for (int b = -1; b <= 1; ++b) {
            int pw = w + b;
            if ((unsigned)pw >= 64u) continue;
            int r = p + a * 64 + b;
            float M = statM[r];
            const u16* rp = in + (size_t)r * LP + l8 + a * W;
            ushort8 v = *reinterpret_cast<const ushort8*>(rp);
            if (b == 0) {
                #pragma unroll
                for (int i = 0; i < 8; ++i) acc[i] += __builtin_amdgcn_exp2f(h162f(v[i]) - M);
            } else if (b == -1) {
                acc[0] += __builtin_amdgcn_exp2f(h162f(rp[-1]) - M);
                #pragma unroll
                for (int i = 1; i < 8; ++i) acc[i] += __builtin_amdgcn_exp2f(h162f(v[i - 1]) - M);
            } else {
                acc[7] += __builtin_amdgcn_exp2f(h162f(rp[8]) - M);
                #pragma unroll
                for (int i = 0; i < 7; ++i) acc[i] += __builtin_amdgcn_exp2f(h162f(v[i + 1]) - M);
            }
        }
    }
    const float4 rn0 = *reinterpret_cast<const float4*>(rnorm + l8);
    const float4 rn1 = *reinterpret_cast<const float4*>(rnorm + l8 + 4);
    float rn[8] = {rn0.x, rn0.y, rn0.z, rn0.w, rn1.x, rn1.y, rn1.z, rn1.w};
    ushort8 res;
    #pragma unroll
    for (int i = 0; i < 8; ++i)
        res[i] = f2bf((rn[i] != 0.f) ? acc[i] : 0.f);
    *reinterpret_cast<ushort8*>(out + (size_t)p * LP + l8) = res;
}

// ---------------------------------------------------------------------------
extern "C" void kernel_launch(void* const* d_in, const int* in_sizes, int n_in,
                              void* d_out, int out_size, void* d_ws, size_t ws_size,
                              hipStream_t stream) {
    const float* x      = (const float*)d_in[0];
    const float* bb0_w  = (const float*)d_in[1];
    const float* bb0_b  = (const float*)d_in[2];
    const float* bb0_a  = (const float*)d_in[3];
    const float* rb1_w1 = (const float*)d_in[4];
    const float* rb1_b1 = (const float*)d_in[5];
    const float* rb1_w2 = (const float*)d_in[6];
    const float* rb1_b2 = (const float*)d_in[7];
    const float* pamb_w = (const float*)d_in[8];
    const float* pamb_b = (const float*)d_in[9];
    const float* pamb_a = (const float*)d_in[10];
    const float* pam_w  = (const float*)d_in[11];
    const float* pam_b  = (const float*)d_in[12];
    const float* pam_a  = (const float*)d_in[13];
    const float* paa_w  = (const float*)d_in[14];
    const float* paa_b  = (const float*)d_in[15];
    const float* paa_a  = (const float*)d_in[16];
    const float* rb2_w1 = (const float*)d_in[17];
    const float* rb2_b1 = (const float*)d_in[18];
    const float* rb2_w2 = (const float*)d_in[19];
    const float* rb2_b2 = (const float*)d_in[20];
    float* out = (float*)d_out;
    (void)in_sizes; (void)n_in; (void)out_size; (void)ws_size;

    char* wp = (char*)d_ws;
    auto alloc = [&](size_t nbytes) { void* p = wp; wp += (nbytes + 255) & ~(size_t)255; return p; };
    const size_t BIG = 4096ull * LP * 2;             // 113 MB
    char* big1r  = (char*)alloc(BIG + 1024);
    char* big2r  = (char*)alloc(BIG + 1024);
    float* h0f   = (float*)alloc(2ull * 64 * 4096 * 4);
    float* h1f   = (float*)alloc(2ull * 128 * 4096 * 4);
    float* h2f   = (float*)alloc(2ull * 128 * 4096 * 4);
    float* paf   = (float*)alloc(2ull * 128 * 4096 * 4);
    float* tbuf  = (float*)alloc(2ull * 128 * 4096 * 4);
    u16* mbT     = (u16*)alloc(2ull * 4096 * 64 * 2);
    u16* refmT   = (u16*)alloc(2ull * LP * 64 * 2);
    u16* baseA   = (u16*)alloc(2ull * 128 * LP * 2);
    float* s2b   = (float*)alloc(2ull * LP * 4);
    float* rnorm = (float*)alloc(2ull * LP * 4);
    float* statM = (float*)alloc(4096ull * 4);
    u16* W1      = (u16*)alloc(256ull * 128 * 2);
    u16* W2      = (u16*)alloc(256ull * 128 * 2);
    float* b1v   = (float*)alloc(256 * 4);
    float* a1v   = (float*)alloc(256 * 4);
    float* b2v   = (float*)alloc(256 * 4);
    float* a2v   = (float*)alloc(256 * 4);
    u16* A0      = (u16*)alloc(73728ull * 2);
    u16* A1      = (u16*)alloc(147456ull * 2);
    u16* A2      = (u16*)alloc(147456ull * 2);
    u16* A3      = (u16*)alloc(147456ull * 2);
    u16* A4      = (u16*)alloc(147456ull * 2);
    // Views inside the big buffers (lifetime-disjoint phases):
    u16* patT    = (u16*)big1r;
    u16* h2T     = (u16*)big1r;                          // [2][4096][128]
    u16* refbT   = (u16*)(big1r + (4ull << 20));         // [2][7808][128]
    u16* S0T     = (u16*)(big1r + 512);
    u16* gT      = (u16*)(big1r + 512);
    float* parts = (float*)big2r;                        // conv fp32 / tconv bf16 partials
    u16* cT1     = (u16*)big2r;                          // [2][4096][256]
    u16* cOut1   = (u16*)(big2r + (4ull << 20));         // [2][256][4096]
    u16* cT2     = (u16*)(big2r + (8ull << 20));         // [2][7808][256]
    u16* cOut2   = (u16*)(big2r + (16ull << 20));        // [2][256][7808]
    float* refb  = (float*)(big2r + (26ull << 20));      // [2][level][128][OS^2]
    u16* scT     = (u16*)(big2r + 512);

    const long h2bs = 128L * 4096;
    const long pMN = 128L * 4096;
    const long refbs = 128L * 7786;
    const long mbTbs = 4096L * 64, rmTbs = (long)LP * 64, baBS = 128L * LP;
    const long cT1bs = 4096L * 256, cO1bs = 256L * 4096;
    const long cT2bs = 7808L * 256, cO2bs = 256L * 7808;
    const long rbTbs = 7808L * 128;

    auto conv = [&](const float* src, const u16* W, int Cin, const float* bias,
                    const float* alpha, int act, const float* resid, float* dst) {
        int K = Cin * 9;
        d7_im2col<<<dim3((K + 255) / 256, 4096, 2), 256, 0, stream>>>(src, patT, Cin, (long)Cin * 4096, 4096L * K);
        d7_gemm<<<dim3(32, 6, 2), 256, 0, stream>>>(W, patT, 4096, K, K / 6, 1, 6,
            0, 4096L * K, nullptr, nullptr, 0, nullptr, 0,
            nullptr, 0, nullptr, 0, nullptr, 0, 0, parts, pMN, 0);
        d7_epi<<<dim3(2048, 1, 2), 256, 0, stream>>>(parts, 6, pMN, 6 * pMN,
            bias, alpha, act, resid, h2bs, 1.0f, dst, h2bs, (int)pMN, 0);
    };

    d7_cast<<<dim3(288), 256, 0, stream>>>(bb0_w, A0, 73728);
    d7_cast<<<dim3(576), 256, 0, stream>>>(rb1_w1, A1, 147456);
    d7_cast<<<dim3(576), 256, 0, stream>>>(rb1_w2, A2, 147456);
    d7_cast<<<dim3(576), 256, 0, stream>>>(rb2_w1, A3, 147456);
    d7_cast<<<dim3(576), 256, 0, stream>>>(rb2_w2, A4, 147456);
    d7_wbuild<<<dim3(128), 256, 0, stream>>>(pamb_w, pam_w, paa_w, pamb_b, pam_b, paa_b,
                                             pamb_a, pam_a, paa_a, W1, W2, b1v, a1v, b2v, a2v);

    d7_maxpool<<<dim3(16, 64, 2), 256, 0, stream>>>(x, h0f);
    conv(h0f, A0, 64, bb0_b, bb0_a, 1, nullptr, h1f);
    conv(h1f, A1, 128, rb1_b1, nullptr, 2, nullptr, tbuf);
    conv(tbuf, A2, 128, rb1_b2, nullptr, 0, h1f, h2f);

    d7_resize<57><<<dim3(13, 128, 2), 256, 0, stream>>>(h2f, refb, refbs);
    d7_resize<51><<<dim3(11, 128, 2), 256, 0, stream>>>(h2f, refb + 3249L * 128, refbs);
    d7_resize<44><<<dim3(8, 128, 2), 256, 0, stream>>>(h2f, refb + 5850L * 128, refbs);

    // p-major bf16 operands for the fused 1x1-conv GEMMs (per-level transpose)
    hipMemsetAsync(refbT, 0, 2ull * rbTbs * 2, stream);
    d7_t32<<<dim3(128, 4, 2), 256, 0, stream>>>(h2f, h2bs, 4096, h2T, 4096L * 128);
    d7_t32<<<dim3(102, 4, 2), 256, 0, stream>>>(refb, refbs, 3249, refbT, rbTbs);
    d7_t32<<<dim3(82, 4, 2), 256, 0, stream>>>(refb + 3249L * 128, refbs, 2601, refbT + 3249L * 128, rbTbs);
    d7_t32<<<dim3(61, 4, 2), 256, 0, stream>>>(refb + 5850L * 128, refbs, 1936, refbT + 5850L * 128, rbTbs);

    // all 1x1 convs as two GEMMs (per-row-alpha prelu), row-major + transposed outputs
    d7_gemm<<<dim3(32, 2, 2), 256, 0, stream>>>(W1, h2T, 4096, 128, 128, 2, 1,
        0, 4096L * 128, b1v, a1v, 3, nullptr, 0,
        nullptr, 0, cOut1, cO1bs, cT1, 256, cT1bs, nullptr, 0, 0);
    d7_gemm<<<dim3(61, 2, 2), 256, 0, stream>>>(W2, refbT, 7808, 128, 128, 2, 1,
        0, rbTbs, b2v, a2v, 3, nullptr, 0,
        nullptr, 0, cOut2, cO2bs, cT2, 256, cT2bs, nullptr, 0, 0);

    // scatter into padded attention layouts (+ fused s2 for refmT)
    hipMemsetAsync(refmT, 0, 2ull * LP * 64 * 2, stream);
    hipMemsetAsync(baseA, 0, 2ull * 128 * LP * 2, stream);
    hipMemsetAsync(s2b, 0, 2ull * LP * 4, stream);
    d7_scK<<<dim3(128, 1, 2), 256, 0, stream>>>(cT1, cT1bs, 256, 0, 0, 4096, 64, 64, -65, mbT, mbTbs, nullptr);
    d7_scK<<<dim3(128, 1, 2), 256, 0, stream>>>(cT1, cT1bs, 256, 64, 0, 4096, 64, 72, 0, refmT, rmTbs, s2b);
    d7_scK<<<dim3(102, 1, 2), 256, 0, stream>>>(cT2, cT2bs, 256, 0, 0, 3249, 57, 64, 4752, refmT, rmTbs, s2b);
    d7_scK<<<dim3(82, 1, 2), 256, 0, stream>>>(cT2, cT2bs, 256, 0, 3249, 2601, 51, 56, 8528, refmT, rmTbs, s2b);
    d7_scK<<<dim3(61, 1, 2), 256, 0, stream>>>(cT2, cT2bs, 256, 0, 5850, 1936, 44, 48, 11496, refmT, rmTbs, s2b);
    d7_scR<<<dim3(16, 128, 2), 256, 0, stream>>>(cOut1, cO1bs, 4096, 128, 0, 4096, 64, 72, 0, baseA, baBS);
    d7_scR<<<dim3(13, 128, 2), 256, 0, stream>>>(cOut2, cO2bs, 7808, 64, 0, 3249, 57, 64, 4752, baseA, baBS);
    d7_scR<<<dim3(11, 128, 2), 256, 0, stream>>>(cOut2, cO2bs, 7808, 64, 3249, 2601, 51, 56, 8528, baseA, baBS);
    d7_scR<<<dim3(8, 128, 2), 256, 0, stream>>>(cOut2, cO2bs, 7808, 64, 5850, 1936, 44, 48, 11496, baseA, baBS);

    d7_rnormk<<<dim3(54, 1, 2), 256, 0, stream>>>(s2b, rnorm);

    for (int b = 0; b < 2; ++b) {
        // S0T[p][l'] via transposed 8B stores: A=refmT (M=LP), B=mbT (N=4096)
        d7_gemm<<<dim3(32, 108, 1), 256, 0, stream>>>(refmT + b * rmTbs, mbT + b * mbTbs,
            4096, 64, 64, 108, 1, 0, 0, nullptr, nullptr, 0, nullptr, 0,
            nullptr, 0, nullptr, 0, S0T, LP, 0, nullptr, 0, 0);
        d7_st1<<<dim3(7, 4096), 256, 0, stream>>>(S0T, scT, rnorm + (size_t)b * LP);
        d7_stats<<<dim3(4096), 256, 0, stream>>>(scT, statM);
        d7_st2<<<dim3(7, 4096), 256, 0, stream>>>(scT, statM, rnorm + (size_t)b * LP, gT);
        // out_pa = h2f + 0.25 * baseA · gT^T  (split-K = 12, bf16 partials)
        d7_gemm<<<dim3(32, 12, 1), 256, 0, stream>>>(baseA + b * baBS, gT,
            4096, LP, LP / 12, 1, 12, 0, 0, nullptr, nullptr, 0, nullptr, 0,
            nullptr, 0, nullptr, 0, nullptr, 0, 0, parts, pMN, 1);
        d7_epi<<<dim3(2048, 1, 1), 256, 0, stream>>>(parts, 12, pMN, 0,
            nullptr, nullptr, 0, h2f + b * h2bs, 0, 0.25f, paf + b * h2bs, 0, (int)pMN, 1);
    }

    conv(paf, A3, 128, rb2_b1, nullptr, 2, nullptr, tbuf);
    conv(tbuf, A4, 128, rb2_b2, nullptr, 0, paf, out);
}